// Round 1
// baseline (1528.240 us; speedup 1.0000x reference)
//
#include <hip/hip_runtime.h>
#include <cstdint>

#define N_NODES 50000
#define N_EDGES 600000
#define HDIM    128
#define NGRAPH  256
#define EPSBN   1e-5f
#define NEG     0.2f

__device__ __forceinline__ float lrelu(float v){ return v > 0.f ? v : NEG*v; }

// monotonic float <-> uint mapping for atomicMax on floats
__device__ __forceinline__ unsigned fkey(float f){
  unsigned u = __float_as_uint(f);
  return (int)u < 0 ? ~u : (u | 0x80000000u);
}
__device__ __forceinline__ float fdec(unsigned k){
  unsigned u = (int)k < 0 ? (k & 0x7fffffffu) : ~k;
  return __uint_as_float(u);
}

// ---------------- GEMM: [N,128] @ [128,128] -> [N,128] ----------------
// block: 256 threads = 16 rows x 16 col-groups(8 cols). W staged in LDS in
// 32-row chunks; X tile (16x128) staged once. 50000 = 3125 * 16 exactly.
__global__ __launch_bounds__(256) void gemm128(const float* __restrict__ X,
                                               const float* __restrict__ W,
                                               float* __restrict__ Y){
  __shared__ float xs[16][132];   // pad 132: breaks bank aliasing on broadcast read
  __shared__ float ws[32][132];
  const int t  = threadIdx.x;
  const int tx = t & 15, ty = t >> 4;
  const long row0 = (long)blockIdx.x * 16;

  {
    const float4* X4 = (const float4*)(X + row0*128);
#pragma unroll
    for (int i = 0; i < 2; ++i){
      int idx = t + i*256;            // 512 float4 = 16x128 floats
      float4 v = X4[idx];
      int r = idx >> 5;
      int c = (idx & 31) * 4;
      xs[r][c] = v.x; xs[r][c+1] = v.y; xs[r][c+2] = v.z; xs[r][c+3] = v.w;
    }
  }
  float acc[8] = {0,0,0,0,0,0,0,0};
  for (int kc = 0; kc < 4; ++kc){
    __syncthreads();
    const float4* W4 = (const float4*)(W + kc*32*128);
#pragma unroll
    for (int i = 0; i < 4; ++i){
      int idx = t + i*256;            // 1024 float4 = 32x128 floats
      float4 v = W4[idx];
      int r = idx >> 5;
      int c = (idx & 31) * 4;
      ws[r][c] = v.x; ws[r][c+1] = v.y; ws[r][c+2] = v.z; ws[r][c+3] = v.w;
    }
    __syncthreads();
#pragma unroll
    for (int k = 0; k < 32; ++k){
      float a = xs[ty][kc*32 + k];
      const float* wr = &ws[k][tx*8];
      float4 w0 = *(const float4*)(wr);
      float4 w1 = *(const float4*)(wr + 4);
      acc[0] += a*w0.x; acc[1] += a*w0.y; acc[2] += a*w0.z; acc[3] += a*w0.w;
      acc[4] += a*w1.x; acc[5] += a*w1.y; acc[6] += a*w1.z; acc[7] += a*w1.w;
    }
  }
  float* yp = Y + (row0 + ty)*128 + tx*8;
  float4 o0 = {acc[0],acc[1],acc[2],acc[3]};
  float4 o1 = {acc[4],acc[5],acc[6],acc[7]};
  *(float4*)yp = o0; *(float4*)(yp+4) = o1;
}

// ---------------- degree / norm ----------------
__global__ void deg_kernel(const int* __restrict__ ei, float* __restrict__ deg){
  int e = blockIdx.x*256 + threadIdx.x;
  if (e < N_EDGES) atomicAdd(&deg[ei[N_EDGES + e]], 1.f);
}
__global__ void dis_kernel(float* __restrict__ deg){
  int i = blockIdx.x*256 + threadIdx.x;
  if (i < N_NODES) deg[i] = rsqrtf(deg[i] + 1.f);   // +1 = self loop; deg>=1
}

// B[i,f] = A[i,f] * dis[i]^2   (GCN self-loop term; also zero-inits B)
__global__ void scale_rows_sq(const float* __restrict__ A, const float* __restrict__ dis,
                              float* __restrict__ B){
  int idx = blockIdx.x*256 + threadIdx.x;
  float d = dis[idx >> 7];
  B[idx] = A[idx]*d*d;
}

// B[dst,f] += A[src,f] * dis[src]*dis[dst]   (one thread per edge-feature)
__global__ void gcn_edge(const int* __restrict__ ei, const float* __restrict__ A,
                         const float* __restrict__ dis, float* __restrict__ B){
  int idx = blockIdx.x*256 + threadIdx.x;
  int e = idx >> 7, f = idx & 127;
  int s = ei[e], d = ei[N_EDGES + e];
  float nm = dis[s]*dis[d];
  atomicAdd(&B[(long)d*128 + f], A[(long)s*128 + f]*nm);
}

// ---------------- BatchNorm (conv bias cancels in BN -> skipped) ----------------
// column sums / sumsq; col = tid&127 stays fixed under grid-stride (step % 128 == 0)
__global__ void stats_kernel(const float* __restrict__ X, const float* __restrict__ rowdiv,
                             float* __restrict__ S, float* __restrict__ Q, int total){
  __shared__ float ss[256], sq[256];
  int t = threadIdx.x;
  float s = 0.f, q = 0.f;
  int stride = gridDim.x * 256;
  for (int idx = blockIdx.x*256 + t; idx < total; idx += stride){
    float v = X[idx];
    if (rowdiv) v /= rowdiv[idx >> 7];
    s += v; q += v*v;
  }
  ss[t] = s; sq[t] = q;
  __syncthreads();
  if (t < 128){
    atomicAdd(&S[t], ss[t] + ss[t+128]);
    atomicAdd(&Q[t], sq[t] + sq[t+128]);
  }
}
__global__ void bnparam(const float* __restrict__ S, const float* __restrict__ Q,
                        const float* __restrict__ g, const float* __restrict__ be,
                        float* __restrict__ sc, float* __restrict__ sh){
  int c = threadIdx.x;
  float mean = S[c] / (float)N_NODES;
  float var  = fmaxf(Q[c]/(float)N_NODES - mean*mean, 0.f);
  float scale = g[c]*rsqrtf(var + EPSBN);
  sc[c] = scale;
  sh[c] = be[c] - mean*scale;
}
__global__ void bn_apply(const float* __restrict__ X, const float* __restrict__ rowdiv,
                         const float* __restrict__ sc, const float* __restrict__ sh,
                         float* __restrict__ Y, int total){
  int idx = blockIdx.x*256 + threadIdx.x;
  if (idx >= total) return;
  float v = X[idx];
  if (rowdiv) v /= rowdiv[idx >> 7];
  int c = idx & 127;
  Y[idx] = fmaxf(v*sc[c] + sh[c], 0.f);
}
// fused BN+ReLU+segment-mean-pool accumulation
__global__ void bn_apply_pool(const float* __restrict__ X,
                              const float* __restrict__ sc, const float* __restrict__ sh,
                              const int* __restrict__ batch,
                              float* __restrict__ pooled, float* __restrict__ cnts, int total){
  int idx = blockIdx.x*256 + threadIdx.x;
  if (idx >= total) return;
  int n = idx >> 7, c = idx & 127;
  float v = fmaxf(X[idx]*sc[c] + sh[c], 0.f);
  int g = batch[n];
  atomicAdd(&pooled[(long)g*128 + c], v);
  if (c == 0) atomicAdd(&cnts[g], 1.f);
}

// ---------------- GAT ----------------
// one wave per node: al_s = h.a_src, al_d = h.a_dst; init running max with self-loop e
__global__ void att_kernel(const float* __restrict__ C,
                           const float* __restrict__ asr, const float* __restrict__ adt,
                           float* __restrict__ al_s, float* __restrict__ al_d,
                           unsigned* __restrict__ mkey){
  int n = blockIdx.x*4 + (threadIdx.x >> 6);
  int l = threadIdx.x & 63;
  const float* row = C + (long)n*128;
  float c0 = row[l], c1 = row[l+64];
  float s = c0*asr[l] + c1*asr[l+64];
  float d = c0*adt[l] + c1*adt[l+64];
  for (int off = 32; off; off >>= 1){
    s += __shfl_down(s, off);
    d += __shfl_down(d, off);
  }
  if (l == 0){
    al_s[n] = s; al_d[n] = d;
    mkey[n] = fkey(lrelu(s + d));    // self-loop seeds the segment max
  }
}
__global__ void gat_max(const int* __restrict__ ei, const float* __restrict__ al_s,
                        const float* __restrict__ al_d, unsigned* __restrict__ mkey){
  int e = blockIdx.x*256 + threadIdx.x;
  if (e >= N_EDGES) return;
  int s = ei[e], d = ei[N_EDGES + e];
  atomicMax(&mkey[d], fkey(lrelu(al_s[s] + al_d[d])));
}
// B = ex_self * C (numerator init), denom = ex_self
__global__ void gat_init(const float* __restrict__ C, const float* __restrict__ al_s,
                         const float* __restrict__ al_d, const unsigned* __restrict__ mkey,
                         float* __restrict__ denom, float* __restrict__ B){
  int idx = blockIdx.x*256 + threadIdx.x;
  int n = idx >> 7, f = idx & 127;
  float m  = fdec(mkey[n]);
  float ex = expf(lrelu(al_s[n] + al_d[n]) - m);
  B[idx] = ex * C[idx];
  if (f == 0) denom[n] = ex;
}
__global__ void gat_edge(const int* __restrict__ ei, const float* __restrict__ C,
                         const float* __restrict__ al_s, const float* __restrict__ al_d,
                         const unsigned* __restrict__ mkey,
                         float* __restrict__ denom, float* __restrict__ B){
  int idx = blockIdx.x*256 + threadIdx.x;
  int e = idx >> 7, f = idx & 127;
  int s = ei[e], d = ei[N_EDGES + e];
  float ex = expf(lrelu(al_s[s] + al_d[d]) - fdec(mkey[d]));
  if (f == 0) atomicAdd(&denom[d], ex);
  atomicAdd(&B[(long)d*128 + f], ex * C[(long)s*128 + f]);
}

// ---------------- MLP head: one block per graph ----------------
__global__ void final_kernel(const float* __restrict__ pooled, const float* __restrict__ cnts,
                             const float* __restrict__ fw1, const float* __restrict__ fb1,
                             const float* __restrict__ fw2, const float* __restrict__ fb2,
                             float* __restrict__ out){
  __shared__ float p[128];
  __shared__ float red[2];
  int g = blockIdx.x, t = threadIdx.x;
  float cnt = fmaxf(cnts[g], 1.f);
  p[t] = pooled[(long)g*128 + t] / cnt;
  __syncthreads();
  float acc = fb1[t];
  for (int k = 0; k < 128; ++k) acc += p[k]*fw1[k*128 + t];
  float z = fmaxf(acc, 0.f) * fw2[t];
  for (int off = 32; off; off >>= 1) z += __shfl_down(z, off);
  if ((t & 63) == 0) red[t >> 6] = z;
  __syncthreads();
  if (t == 0) out[g] = red[0] + red[1] + fb2[0];
}

extern "C" void kernel_launch(void* const* d_in, const int* in_sizes, int n_in,
                              void* d_out, int out_size, void* d_ws, size_t ws_size,
                              hipStream_t stream){
  const float* x    = (const float*)d_in[0];
  const int*   ei   = (const int*)d_in[1];
  const int*   batch= (const int*)d_in[2];
  const float* W1   = (const float*)d_in[3];
  const float* g1   = (const float*)d_in[5];
  const float* be1  = (const float*)d_in[6];
  const float* Wg   = (const float*)d_in[7];
  const float* asr  = (const float*)d_in[8];
  const float* adt  = (const float*)d_in[9];
  const float* g2   = (const float*)d_in[11];
  const float* be2  = (const float*)d_in[12];
  const float* W3   = (const float*)d_in[13];
  const float* g3   = (const float*)d_in[15];
  const float* be3  = (const float*)d_in[16];
  const float* fw1  = (const float*)d_in[17];
  const float* fb1  = (const float*)d_in[18];
  const float* fw2  = (const float*)d_in[19];
  const float* fb2  = (const float*)d_in[20];
  float* out = (float*)d_out;

  const long NH = (long)N_NODES*HDIM;
  float* ws     = (float*)d_ws;
  float* A      = ws;                         // [N,H]
  float* B      = A + NH;                     // [N,H]
  float* C      = B + NH;                     // [N,H]
  float* dis    = C + NH;                     // [N]  (deg -> rsqrt in place)
  float* stats  = dis + N_NODES;              // 6*128 (S1 Q1 S2 Q2 S3 Q3)
  float* pooled = stats + 768;                // [G,H]
  float* cnts   = pooled + (long)NGRAPH*HDIM; // [G]
  float* al_s   = cnts + NGRAPH;              // [N]
  float* al_d   = al_s + N_NODES;             // [N]
  unsigned* mkey= (unsigned*)(al_d + N_NODES);// [N]
  float* denom  = (float*)mkey + N_NODES;     // [N]
  float* sc     = denom + N_NODES;            // [128]
  float* sh     = sc + HDIM;                  // [128]

  // zero the accumulator region: dis + stats + pooled + cnts
  size_t zbytes = (size_t)(N_NODES + 768 + (long)NGRAPH*HDIM + NGRAPH) * sizeof(float);
  hipMemsetAsync(dis, 0, zbytes, stream);

  const int TB = 256;
  const int gE  = (N_EDGES + TB - 1)/TB;
  const int gN  = (N_NODES + TB - 1)/TB;
  const int gNH = (int)(NH / TB);             // 25000 (exact)
  const int gEH = (int)((long)N_EDGES*HDIM / TB); // 300000 (exact)
  const int gG  = N_NODES / 16;               // 3125 (exact)

  deg_kernel<<<gE, TB, 0, stream>>>(ei, dis);
  dis_kernel<<<gN, TB, 0, stream>>>(dis);

  // ---- layer 1: GCN + BN + ReLU ----
  gemm128<<<gG, TB, 0, stream>>>(x, W1, A);
  scale_rows_sq<<<gNH, TB, 0, stream>>>(A, dis, B);
  gcn_edge<<<gEH, TB, 0, stream>>>(ei, A, dis, B);
  stats_kernel<<<1024, TB, 0, stream>>>(B, nullptr, stats + 0, stats + 128, (int)NH);
  bnparam<<<1, 128, 0, stream>>>(stats + 0, stats + 128, g1, be1, sc, sh);
  bn_apply<<<gNH, TB, 0, stream>>>(B, nullptr, sc, sh, A, (int)NH);

  // ---- layer 2: GAT + BN + ReLU ----
  gemm128<<<gG, TB, 0, stream>>>(A, Wg, C);
  att_kernel<<<N_NODES/4, TB, 0, stream>>>(C, asr, adt, al_s, al_d, mkey);
  gat_max<<<gE, TB, 0, stream>>>(ei, al_s, al_d, mkey);
  gat_init<<<gNH, TB, 0, stream>>>(C, al_s, al_d, mkey, denom, B);
  gat_edge<<<gEH, TB, 0, stream>>>(ei, C, al_s, al_d, mkey, denom, B);
  stats_kernel<<<1024, TB, 0, stream>>>(B, denom, stats + 256, stats + 384, (int)NH);
  bnparam<<<1, 128, 0, stream>>>(stats + 256, stats + 384, g2, be2, sc, sh);
  bn_apply<<<gNH, TB, 0, stream>>>(B, denom, sc, sh, A, (int)NH);

  // ---- layer 3: GCN + BN + ReLU + pool ----
  gemm128<<<gG, TB, 0, stream>>>(A, W3, C);
  scale_rows_sq<<<gNH, TB, 0, stream>>>(C, dis, B);
  gcn_edge<<<gEH, TB, 0, stream>>>(ei, C, dis, B);
  stats_kernel<<<1024, TB, 0, stream>>>(B, nullptr, stats + 512, stats + 640, (int)NH);
  bnparam<<<1, 128, 0, stream>>>(stats + 512, stats + 640, g3, be3, sc, sh);
  bn_apply_pool<<<gNH, TB, 0, stream>>>(B, sc, sh, batch, pooled, cnts, (int)NH);

  // ---- MLP head ----
  final_kernel<<<NGRAPH, 128, 0, stream>>>(pooled, cnts, fw1, fb1, fw2, fb2, out);
}

// Round 2
// 953.723 us; speedup vs baseline: 1.6024x; 1.6024x over previous
//
#include <hip/hip_runtime.h>
#include <cstdint>

#define N_NODES 50000
#define N_EDGES 600000
#define HDIM    128
#define NGRAPH  256
#define EPSBN   1e-5f
#define NEG     0.2f
#define SCAN_B  196   // ceil(50000/256)

__device__ __forceinline__ float lrelu(float v){ return v > 0.f ? v : NEG*v; }

// ---------------- GEMM: [N,128] @ [128,128] -> [N,128] ----------------
__global__ __launch_bounds__(256) void gemm128(const float* __restrict__ X,
                                               const float* __restrict__ W,
                                               float* __restrict__ Y){
  __shared__ float xs[16][132];
  __shared__ float ws[32][132];
  const int t  = threadIdx.x;
  const int tx = t & 15, ty = t >> 4;
  const long row0 = (long)blockIdx.x * 16;

  {
    const float4* X4 = (const float4*)(X + row0*128);
#pragma unroll
    for (int i = 0; i < 2; ++i){
      int idx = t + i*256;
      float4 v = X4[idx];
      int r = idx >> 5;
      int c = (idx & 31) * 4;
      xs[r][c] = v.x; xs[r][c+1] = v.y; xs[r][c+2] = v.z; xs[r][c+3] = v.w;
    }
  }
  float acc[8] = {0,0,0,0,0,0,0,0};
  for (int kc = 0; kc < 4; ++kc){
    __syncthreads();
    const float4* W4 = (const float4*)(W + kc*32*128);
#pragma unroll
    for (int i = 0; i < 4; ++i){
      int idx = t + i*256;
      float4 v = W4[idx];
      int r = idx >> 5;
      int c = (idx & 31) * 4;
      ws[r][c] = v.x; ws[r][c+1] = v.y; ws[r][c+2] = v.z; ws[r][c+3] = v.w;
    }
    __syncthreads();
#pragma unroll
    for (int k = 0; k < 32; ++k){
      float a = xs[ty][kc*32 + k];
      const float* wr = &ws[k][tx*8];
      float4 w0 = *(const float4*)(wr);
      float4 w1 = *(const float4*)(wr + 4);
      acc[0] += a*w0.x; acc[1] += a*w0.y; acc[2] += a*w0.z; acc[3] += a*w0.w;
      acc[4] += a*w1.x; acc[5] += a*w1.y; acc[6] += a*w1.z; acc[7] += a*w1.w;
    }
  }
  float* yp = Y + (row0 + ty)*128 + tx*8;
  float4 o0 = {acc[0],acc[1],acc[2],acc[3]};
  float4 o1 = {acc[4],acc[5],acc[6],acc[7]};
  *(float4*)yp = o0; *(float4*)(yp+4) = o1;
}

// ---------------- CSR build ----------------
__global__ void deg_kernel(const int* __restrict__ ei, int* __restrict__ degi){
  int e = blockIdx.x*256 + threadIdx.x;
  if (e < N_EDGES) atomicAdd(&degi[ei[N_EDGES + e]], 1);
}
__global__ void dis_kernel(const int* __restrict__ degi, float* __restrict__ dis){
  int i = blockIdx.x*256 + threadIdx.x;
  if (i < N_NODES) dis[i] = rsqrtf((float)degi[i] + 1.f);   // +1 = self loop
}
__global__ void scan_partial(const int* __restrict__ degi, int* __restrict__ part){
  __shared__ int sm[256];
  int t = threadIdx.x; int i = blockIdx.x*256 + t;
  sm[t] = (i < N_NODES) ? degi[i] : 0;
  __syncthreads();
  for (int off = 128; off; off >>= 1){
    if (t < off) sm[t] += sm[t + off];
    __syncthreads();
  }
  if (t == 0) part[blockIdx.x] = sm[0];
}
__global__ void scan_offsets(int* part){
  __shared__ int sm[256];
  int t = threadIdx.x;
  int v = (t < SCAN_B) ? part[t] : 0;
  sm[t] = v; __syncthreads();
  for (int off = 1; off < 256; off <<= 1){
    int add = (t >= off) ? sm[t - off] : 0;
    __syncthreads();
    sm[t] += add; __syncthreads();
  }
  if (t < SCAN_B) part[t] = sm[t] - v;   // exclusive chunk offsets
}
__global__ void scan_final(const int* __restrict__ degi, const int* __restrict__ part,
                           int* __restrict__ rowp){
  __shared__ int sm[256];
  int t = threadIdx.x; int i = blockIdx.x*256 + t;
  int v = (i < N_NODES) ? degi[i] : 0;
  sm[t] = v; __syncthreads();
  for (int off = 1; off < 256; off <<= 1){
    int add = (t >= off) ? sm[t - off] : 0;
    __syncthreads();
    sm[t] += add; __syncthreads();
  }
  if (i < N_NODES) rowp[i] = part[blockIdx.x] + sm[t] - v;  // exclusive prefix
}
__global__ void csr_scatter(const int* __restrict__ ei, const int* __restrict__ rowp,
                            int* __restrict__ fill, int* __restrict__ colx){
  int e = blockIdx.x*256 + threadIdx.x;
  if (e >= N_EDGES) return;
  int s = ei[e], d = ei[N_EDGES + e];
  int pos = rowp[d] + atomicAdd(&fill[d], 1);
  colx[pos] = s;
}

// ---------------- GCN aggregation: gather + register accumulate ----------------
// B[n,f] = ( A[n,f]*dis[n] + sum_{s in nbr(n)} A[s,f]*dis[s] ) * dis[n]
__global__ __launch_bounds__(256) void gcn_agg(const float* __restrict__ A,
    const float* __restrict__ dis, const int* __restrict__ rowp,
    const int* __restrict__ degi, const int* __restrict__ colx,
    float* __restrict__ B){
  int n = blockIdx.x*2 + (threadIdx.x >> 7);
  int f = threadIdx.x & 127;
  float dn = dis[n];
  float acc = A[(long)n*128 + f] * dn;
  int e0 = rowp[n], cnt = degi[n];
  for (int e = e0; e < e0 + cnt; ++e){
    int s = colx[e];
    acc += dis[s] * A[(long)s*128 + f];
  }
  B[(long)n*128 + f] = acc * dn;
}

// ---------------- GAT ----------------
__global__ void att_kernel(const float* __restrict__ C,
                           const float* __restrict__ asr, const float* __restrict__ adt,
                           float* __restrict__ al_s, float* __restrict__ al_d){
  int n = blockIdx.x*4 + (threadIdx.x >> 6);
  int l = threadIdx.x & 63;
  const float* row = C + (long)n*128;
  float c0 = row[l], c1 = row[l+64];
  float s = c0*asr[l] + c1*asr[l+64];
  float d = c0*adt[l] + c1*adt[l+64];
  for (int off = 32; off; off >>= 1){
    s += __shfl_down(s, off);
    d += __shfl_down(d, off);
  }
  if (l == 0){ al_s[n] = s; al_d[n] = d; }
}
// softmax-weighted gather; no atomics, denom/max computed per node in-register
__global__ __launch_bounds__(256) void gat_agg(const float* __restrict__ C,
    const float* __restrict__ al_s, const float* __restrict__ al_d,
    const int* __restrict__ rowp, const int* __restrict__ degi,
    const int* __restrict__ colx, float* __restrict__ B){
  int n = blockIdx.x*2 + (threadIdx.x >> 7);
  int f = threadIdx.x & 127;
  float adn = al_d[n];
  float lself = lrelu(al_s[n] + adn);
  int e0 = rowp[n], cnt = degi[n];
  float m = lself;
  for (int e = e0; e < e0 + cnt; ++e)
    m = fmaxf(m, lrelu(al_s[colx[e]] + adn));
  float ex = __expf(lself - m);
  float denom = ex;
  float acc = ex * C[(long)n*128 + f];
  for (int e = e0; e < e0 + cnt; ++e){
    int s = colx[e];
    float w = __expf(lrelu(al_s[s] + adn) - m);
    denom += w;
    acc += w * C[(long)s*128 + f];
  }
  B[(long)n*128 + f] = acc / denom;
}

// ---------------- BatchNorm (conv bias cancels in BN -> skipped) ----------------
__global__ void stats_kernel(const float* __restrict__ X,
                             float* __restrict__ S, float* __restrict__ Q, int total){
  __shared__ float ss[256], sq[256];
  int t = threadIdx.x;
  float s = 0.f, q = 0.f;
  int stride = gridDim.x * 256;
  for (int idx = blockIdx.x*256 + t; idx < total; idx += stride){
    float v = X[idx];
    s += v; q += v*v;
  }
  ss[t] = s; sq[t] = q;
  __syncthreads();
  if (t < 128){
    atomicAdd(&S[t], ss[t] + ss[t+128]);
    atomicAdd(&Q[t], sq[t] + sq[t+128]);
  }
}
__global__ void bnparam(const float* __restrict__ S, const float* __restrict__ Q,
                        const float* __restrict__ g, const float* __restrict__ be,
                        float* __restrict__ sc, float* __restrict__ sh){
  int c = threadIdx.x;
  float mean = S[c] / (float)N_NODES;
  float var  = fmaxf(Q[c]/(float)N_NODES - mean*mean, 0.f);
  float scale = g[c]*rsqrtf(var + EPSBN);
  sc[c] = scale;
  sh[c] = be[c] - mean*scale;
}
__global__ void bn_apply(const float* __restrict__ X,
                         const float* __restrict__ sc, const float* __restrict__ sh,
                         float* __restrict__ Y, int total){
  int idx = blockIdx.x*256 + threadIdx.x;
  if (idx >= total) return;
  int c = idx & 127;
  Y[idx] = fmaxf(X[idx]*sc[c] + sh[c], 0.f);
}

// ---------------- pooling: batch is sorted -> segment boundaries ----------------
__global__ void bounds_kernel(const int* __restrict__ batch, int* __restrict__ start){
  int i = blockIdx.x*256 + threadIdx.x;
  if (i >= N_NODES) return;
  int b = batch[i];
  int p = (i == 0) ? -1 : batch[i-1];
  for (int g = p+1; g <= b; ++g) start[g] = i;
  if (i == N_NODES-1)
    for (int g = b+1; g <= NGRAPH; ++g) start[g] = N_NODES;
}
__global__ void pool_kernel(const float* __restrict__ H, const int* __restrict__ start,
                            float* __restrict__ pooled){
  int g = blockIdx.x, f = threadIdx.x;
  int s0 = start[g], s1 = start[g+1];
  float acc = 0.f;
  for (int n = s0; n < s1; ++n) acc += H[(long)n*128 + f];
  pooled[(long)g*128 + f] = acc / fmaxf((float)(s1 - s0), 1.f);
}

// ---------------- MLP head ----------------
__global__ void final_kernel(const float* __restrict__ pooled,
                             const float* __restrict__ fw1, const float* __restrict__ fb1,
                             const float* __restrict__ fw2, const float* __restrict__ fb2,
                             float* __restrict__ out){
  __shared__ float p[128];
  __shared__ float red[2];
  int g = blockIdx.x, t = threadIdx.x;
  p[t] = pooled[(long)g*128 + t];
  __syncthreads();
  float acc = fb1[t];
  for (int k = 0; k < 128; ++k) acc += p[k]*fw1[k*128 + t];
  float z = fmaxf(acc, 0.f) * fw2[t];
  for (int off = 32; off; off >>= 1) z += __shfl_down(z, off);
  if ((t & 63) == 0) red[t >> 6] = z;
  __syncthreads();
  if (t == 0) out[g] = red[0] + red[1] + fb2[0];
}

extern "C" void kernel_launch(void* const* d_in, const int* in_sizes, int n_in,
                              void* d_out, int out_size, void* d_ws, size_t ws_size,
                              hipStream_t stream){
  const float* x    = (const float*)d_in[0];
  const int*   ei   = (const int*)d_in[1];
  const int*   batch= (const int*)d_in[2];
  const float* W1   = (const float*)d_in[3];
  const float* g1   = (const float*)d_in[5];
  const float* be1  = (const float*)d_in[6];
  const float* Wg   = (const float*)d_in[7];
  const float* asr  = (const float*)d_in[8];
  const float* adt  = (const float*)d_in[9];
  const float* g2   = (const float*)d_in[11];
  const float* be2  = (const float*)d_in[12];
  const float* W3   = (const float*)d_in[13];
  const float* g3   = (const float*)d_in[15];
  const float* be3  = (const float*)d_in[16];
  const float* fw1  = (const float*)d_in[17];
  const float* fb1  = (const float*)d_in[18];
  const float* fw2  = (const float*)d_in[19];
  const float* fb2  = (const float*)d_in[20];
  float* out = (float*)d_out;

  const long NH = (long)N_NODES*HDIM;
  float* ws     = (float*)d_ws;
  float* A      = ws;                          // [N,H] gemm out
  float* B      = A + NH;                      // [N,H] agg out / activations
  float* dis    = B + NH;                      // [N]
  float* al_s   = dis + N_NODES;               // [N]
  float* al_d   = al_s + N_NODES;              // [N]
  float* pooled = al_d + N_NODES;              // [G,H]
  float* sc     = pooled + (long)NGRAPH*HDIM;  // [128]
  float* sh     = sc + HDIM;                   // [128]
  int* deg_i    = (int*)(sh + HDIM);           // [N]   } zeroed
  int* fill     = deg_i + N_NODES;             // [N]   } zeroed
  float* stats  = (float*)(fill + N_NODES);    // [768] } zeroed
  int* rowp     = (int*)(stats + 768);         // [N]
  int* colx     = rowp + N_NODES;              // [E]
  int* start    = colx + N_EDGES;              // [G+1]
  int* part     = start + NGRAPH + 1;          // [256]

  // zero the atomic-accumulated region: deg_i + fill + stats
  hipMemsetAsync(deg_i, 0, (size_t)(2*N_NODES + 768) * sizeof(int), stream);

  const int TB = 256;
  const int gE  = (N_EDGES + TB - 1)/TB;       // 2344
  const int gN  = (N_NODES + TB - 1)/TB;       // 196
  const int gNH = (int)(NH / TB);              // 25000
  const int gG  = N_NODES / 16;                // 3125
  const int gAgg= N_NODES / 2;                 // 25000

  // ---- CSR build (once; graph shared by all 3 layers) ----
  deg_kernel<<<gE, TB, 0, stream>>>(ei, deg_i);
  dis_kernel<<<gN, TB, 0, stream>>>(deg_i, dis);
  scan_partial<<<SCAN_B, TB, 0, stream>>>(deg_i, part);
  scan_offsets<<<1, TB, 0, stream>>>(part);
  scan_final<<<SCAN_B, TB, 0, stream>>>(deg_i, part, rowp);
  csr_scatter<<<gE, TB, 0, stream>>>(ei, rowp, fill, colx);
  bounds_kernel<<<gN, TB, 0, stream>>>(batch, start);

  // ---- layer 1: GCN + BN + ReLU ----
  gemm128<<<gG, TB, 0, stream>>>(x, W1, A);
  gcn_agg<<<gAgg, TB, 0, stream>>>(A, dis, rowp, deg_i, colx, B);
  stats_kernel<<<1024, TB, 0, stream>>>(B, stats + 0, stats + 128, (int)NH);
  bnparam<<<1, 128, 0, stream>>>(stats + 0, stats + 128, g1, be1, sc, sh);
  bn_apply<<<gNH, TB, 0, stream>>>(B, sc, sh, B, (int)NH);

  // ---- layer 2: GAT + BN + ReLU ----
  gemm128<<<gG, TB, 0, stream>>>(B, Wg, A);
  att_kernel<<<N_NODES/4, TB, 0, stream>>>(A, asr, adt, al_s, al_d);
  gat_agg<<<gAgg, TB, 0, stream>>>(A, al_s, al_d, rowp, deg_i, colx, B);
  stats_kernel<<<1024, TB, 0, stream>>>(B, stats + 256, stats + 384, (int)NH);
  bnparam<<<1, 128, 0, stream>>>(stats + 256, stats + 384, g2, be2, sc, sh);
  bn_apply<<<gNH, TB, 0, stream>>>(B, sc, sh, B, (int)NH);

  // ---- layer 3: GCN + BN + ReLU ----
  gemm128<<<gG, TB, 0, stream>>>(B, W3, A);
  gcn_agg<<<gAgg, TB, 0, stream>>>(A, dis, rowp, deg_i, colx, B);
  stats_kernel<<<1024, TB, 0, stream>>>(B, stats + 512, stats + 640, (int)NH);
  bnparam<<<1, 128, 0, stream>>>(stats + 512, stats + 640, g3, be3, sc, sh);
  bn_apply<<<gNH, TB, 0, stream>>>(B, sc, sh, B, (int)NH);

  // ---- pool + MLP head ----
  pool_kernel<<<NGRAPH, 128, 0, stream>>>(B, start, pooled);
  final_kernel<<<NGRAPH, 128, 0, stream>>>(pooled, fw1, fb1, fw2, fb2, out);
}

// Round 3
// 613.072 us; speedup vs baseline: 2.4928x; 1.5556x over previous
//
#include <hip/hip_runtime.h>
#include <hip/hip_fp16.h>
#include <cstdint>

#define N_NODES 50000
#define N_EDGES 600000
#define HDIM    128
#define NGRAPH  256
#define EPSBN   1e-5f
#define NEG     0.2f
#define SCAN_B  196   // ceil(50000/256)

__device__ __forceinline__ float lrelu(float v){ return v > 0.f ? v : NEG*v; }

// ============ GEMM layer 1: fp32 X in, fp16 out ============
__global__ __launch_bounds__(256) void gemm_f32(const float* __restrict__ X,
                                                const float* __restrict__ W,
                                                __half* __restrict__ Yh){
  __shared__ float xs[16][132];
  __shared__ float ws[32][132];
  const int t  = threadIdx.x;
  const int tx = t & 15, ty = t >> 4;
  const int row0 = blockIdx.x * 16;
  {
    const float4* X4 = (const float4*)(X + (long)row0*128);
#pragma unroll
    for (int i = 0; i < 2; ++i){
      int idx = t + i*256;
      float4 v = X4[idx];
      int r = idx >> 5, c = (idx & 31)*4;
      xs[r][c]=v.x; xs[r][c+1]=v.y; xs[r][c+2]=v.z; xs[r][c+3]=v.w;
    }
  }
  float acc[8] = {0,0,0,0,0,0,0,0};
  for (int kc = 0; kc < 4; ++kc){
    __syncthreads();
    const float4* W4 = (const float4*)(W + kc*32*128);
#pragma unroll
    for (int i = 0; i < 4; ++i){
      int idx = t + i*256;
      float4 v = W4[idx];
      int r = idx >> 5, c = (idx & 31)*4;
      ws[r][c]=v.x; ws[r][c+1]=v.y; ws[r][c+2]=v.z; ws[r][c+3]=v.w;
    }
    __syncthreads();
#pragma unroll
    for (int k = 0; k < 32; ++k){
      float a = xs[ty][kc*32 + k];
      const float* wr = &ws[k][tx*8];
      float4 w0 = *(const float4*)(wr);
      float4 w1 = *(const float4*)(wr + 4);
      acc[0]+=a*w0.x; acc[1]+=a*w0.y; acc[2]+=a*w0.z; acc[3]+=a*w0.w;
      acc[4]+=a*w1.x; acc[5]+=a*w1.y; acc[6]+=a*w1.z; acc[7]+=a*w1.w;
    }
  }
  union { uint4 u; __half2 h[4]; } pk;
  pk.h[0]=__floats2half2_rn(acc[0],acc[1]); pk.h[1]=__floats2half2_rn(acc[2],acc[3]);
  pk.h[2]=__floats2half2_rn(acc[4],acc[5]); pk.h[3]=__floats2half2_rn(acc[6],acc[7]);
  *(uint4*)(Yh + (long)(row0+ty)*128 + tx*8) = pk.u;
}

// ============ GEMM layers 2/3: fp16 X + fused BN+ReLU on load; optional att epilogue ============
__global__ __launch_bounds__(256) void gemm_h(const __half* __restrict__ Xh,
                                              const float* __restrict__ W,
                                              const float* __restrict__ sc,
                                              const float* __restrict__ sh,
                                              __half* __restrict__ Yh,
                                              float* __restrict__ al_s,
                                              float* __restrict__ al_d,
                                              const float* __restrict__ asr,
                                              const float* __restrict__ adt){
  __shared__ float xs[16][132];
  __shared__ float ws[32][132];
  const int t  = threadIdx.x;
  const int tx = t & 15, ty = t >> 4;
  const int row0 = blockIdx.x * 16;
  {
#pragma unroll
    for (int i = 0; i < 2; ++i){
      int idx = t + i*256;           // 512 x (4 halves)
      int r = idx >> 5, cg = idx & 31;
      uint2 u = ((const uint2*)(Xh + (long)(row0+r)*128))[cg];
      __half2 h01 = *(__half2*)&u.x;
      __half2 h23 = *(__half2*)&u.y;
      float2 f01 = __half22float2(h01);
      float2 f23 = __half22float2(h23);
      float4 s4 = ((const float4*)sc)[cg];
      float4 h4 = ((const float4*)sh)[cg];
      int c = cg*4;
      xs[r][c]   = fmaxf(f01.x*s4.x + h4.x, 0.f);
      xs[r][c+1] = fmaxf(f01.y*s4.y + h4.y, 0.f);
      xs[r][c+2] = fmaxf(f23.x*s4.z + h4.z, 0.f);
      xs[r][c+3] = fmaxf(f23.y*s4.w + h4.w, 0.f);
    }
  }
  float acc[8] = {0,0,0,0,0,0,0,0};
  for (int kc = 0; kc < 4; ++kc){
    __syncthreads();
    const float4* W4 = (const float4*)(W + kc*32*128);
#pragma unroll
    for (int i = 0; i < 4; ++i){
      int idx = t + i*256;
      float4 v = W4[idx];
      int r = idx >> 5, c = (idx & 31)*4;
      ws[r][c]=v.x; ws[r][c+1]=v.y; ws[r][c+2]=v.z; ws[r][c+3]=v.w;
    }
    __syncthreads();
#pragma unroll
    for (int k = 0; k < 32; ++k){
      float a = xs[ty][kc*32 + k];
      const float* wr = &ws[k][tx*8];
      float4 w0 = *(const float4*)(wr);
      float4 w1 = *(const float4*)(wr + 4);
      acc[0]+=a*w0.x; acc[1]+=a*w0.y; acc[2]+=a*w0.z; acc[3]+=a*w0.w;
      acc[4]+=a*w1.x; acc[5]+=a*w1.y; acc[6]+=a*w1.z; acc[7]+=a*w1.w;
    }
  }
  union { uint4 u; __half2 h[4]; } pk;
  pk.h[0]=__floats2half2_rn(acc[0],acc[1]); pk.h[1]=__floats2half2_rn(acc[2],acc[3]);
  pk.h[2]=__floats2half2_rn(acc[4],acc[5]); pk.h[3]=__floats2half2_rn(acc[6],acc[7]);
  *(uint4*)(Yh + (long)(row0+ty)*128 + tx*8) = pk.u;

  if (asr){   // fused attention logits (layer 2): al = Y row . a
    float4 a0 = ((const float4*)asr)[tx*2], a1 = ((const float4*)asr)[tx*2+1];
    float4 b0 = ((const float4*)adt)[tx*2], b1 = ((const float4*)adt)[tx*2+1];
    float s = acc[0]*a0.x + acc[1]*a0.y + acc[2]*a0.z + acc[3]*a0.w
            + acc[4]*a1.x + acc[5]*a1.y + acc[6]*a1.z + acc[7]*a1.w;
    float d = acc[0]*b0.x + acc[1]*b0.y + acc[2]*b0.z + acc[3]*b0.w
            + acc[4]*b1.x + acc[5]*b1.y + acc[6]*b1.z + acc[7]*b1.w;
#pragma unroll
    for (int off = 8; off; off >>= 1){
      s += __shfl_xor(s, off);
      d += __shfl_xor(d, off);
    }
    if (tx == 0){ al_s[row0+ty] = s; al_d[row0+ty] = d; }
  }
}

// ============ CSR build ============
__global__ void deg_kernel(const int* __restrict__ ei, int* __restrict__ degi){
  int e = blockIdx.x*256 + threadIdx.x;
  if (e < N_EDGES) atomicAdd(&degi[ei[N_EDGES + e]], 1);
}
__global__ void dis_kernel(const int* __restrict__ degi, float* __restrict__ dis){
  int i = blockIdx.x*256 + threadIdx.x;
  if (i < N_NODES) dis[i] = rsqrtf((float)degi[i] + 1.f);
}
__global__ void scan_partial(const int* __restrict__ degi, int* __restrict__ part){
  __shared__ int sm[256];
  int t = threadIdx.x; int i = blockIdx.x*256 + t;
  sm[t] = (i < N_NODES) ? degi[i] : 0;
  __syncthreads();
  for (int off = 128; off; off >>= 1){
    if (t < off) sm[t] += sm[t + off];
    __syncthreads();
  }
  if (t == 0) part[blockIdx.x] = sm[0];
}
__global__ void scan_offsets(int* part){
  __shared__ int sm[256];
  int t = threadIdx.x;
  int v = (t < SCAN_B) ? part[t] : 0;
  sm[t] = v; __syncthreads();
  for (int off = 1; off < 256; off <<= 1){
    int add = (t >= off) ? sm[t - off] : 0;
    __syncthreads();
    sm[t] += add; __syncthreads();
  }
  if (t < SCAN_B) part[t] = sm[t] - v;
}
__global__ void scan_final(const int* __restrict__ degi, const int* __restrict__ part,
                           int* __restrict__ rowp){
  __shared__ int sm[256];
  int t = threadIdx.x; int i = blockIdx.x*256 + t;
  int v = (i < N_NODES) ? degi[i] : 0;
  sm[t] = v; __syncthreads();
  for (int off = 1; off < 256; off <<= 1){
    int add = (t >= off) ? sm[t - off] : 0;
    __syncthreads();
    sm[t] += add; __syncthreads();
  }
  if (i < N_NODES) rowp[i] = part[blockIdx.x] + sm[t] - v;
}
__global__ void csr_scatter(const int* __restrict__ ei, const int* __restrict__ rowp,
                            int* __restrict__ fill, int* __restrict__ colx){
  int e = blockIdx.x*256 + threadIdx.x;
  if (e >= N_EDGES) return;
  int s = ei[e], d = ei[N_EDGES + e];
  int pos = rowp[d] + atomicAdd(&fill[d], 1);
  colx[pos] = s;
}

// ============ GCN aggregation: wave per node, lane-broadcast gather ============
__global__ __launch_bounds__(256) void gcn_agg(const __half2* __restrict__ Ah2,
    const float* __restrict__ dis, const int* __restrict__ rowp,
    const int* __restrict__ degi, const int* __restrict__ colx,
    __half2* __restrict__ Bh2){
  const int n = blockIdx.x*4 + (threadIdx.x >> 6);
  const int lane = threadIdx.x & 63;
  const float dn = dis[n];
  float2 self = __half22float2(Ah2[n*64 + lane]);
  float accx = self.x * dn, accy = self.y * dn;
  const int e0 = rowp[n], cnt = degi[n];
  for (int base = 0; base < cnt; base += 64){
    int idx = base + lane;
    int s = 0; float w = 0.f;
    if (idx < cnt){ s = colx[e0 + idx]; w = dis[s]; }
    int lim = min(64, cnt - base);
    for (int j = 0; j < lim; ++j){
      int   sj = __shfl(s, j);
      float wj = __shfl(w, j);
      float2 f = __half22float2(Ah2[sj*64 + lane]);
      accx += wj * f.x; accy += wj * f.y;
    }
  }
  Bh2[n*64 + lane] = __floats2half2_rn(accx * dn, accy * dn);
}

// ============ GAT aggregation: wave per node, 1 exp/edge ============
__global__ __launch_bounds__(256) void gat_agg(const __half2* __restrict__ Ah2,
    const float* __restrict__ al_s, const float* __restrict__ al_d,
    const int* __restrict__ rowp, const int* __restrict__ degi,
    const int* __restrict__ colx, __half2* __restrict__ Bh2){
  const int n = blockIdx.x*4 + (threadIdx.x >> 6);
  const int lane = threadIdx.x & 63;
  const float adn = al_d[n];
  const float lself = lrelu(al_s[n] + adn);
  const int e0 = rowp[n], cnt = degi[n];
  // pass 1: segment max (self included)
  float m = lself;
  for (int base = 0; base < cnt; base += 64){
    int idx = base + lane;
    if (idx < cnt) m = fmaxf(m, lrelu(al_s[colx[e0 + idx]] + adn));
  }
#pragma unroll
  for (int off = 32; off; off >>= 1) m = fmaxf(m, __shfl_xor(m, off));
  // pass 2: weights + gather
  float exs = __expf(lself - m);
  float2 self = __half22float2(Ah2[n*64 + lane]);
  float accx = exs*self.x, accy = exs*self.y;
  float dpart = 0.f;
  for (int base = 0; base < cnt; base += 64){
    int idx = base + lane;
    int s = 0; float w = 0.f;
    if (idx < cnt){ s = colx[e0 + idx]; w = __expf(lrelu(al_s[s] + adn) - m); }
    dpart += w;
    int lim = min(64, cnt - base);
    for (int j = 0; j < lim; ++j){
      int   sj = __shfl(s, j);
      float wj = __shfl(w, j);
      float2 f = __half22float2(Ah2[sj*64 + lane]);
      accx += wj * f.x; accy += wj * f.y;
    }
  }
#pragma unroll
  for (int off = 32; off; off >>= 1) dpart += __shfl_xor(dpart, off);
  float r = 1.f / (dpart + exs);
  Bh2[n*64 + lane] = __floats2half2_rn(accx * r, accy * r);
}

// ============ BN stats over fp16 tensor ============
__global__ void stats_h(const __half2* __restrict__ X2,
                        float* __restrict__ S, float* __restrict__ Q){
  __shared__ float s0m[256], s1m[256], q0m[256], q1m[256];
  int t = threadIdx.x;
  float s0=0,s1=0,q0=0,q1=0;
  int stride = gridDim.x*256;
  const int total = N_NODES*64;
  for (int idx = blockIdx.x*256 + t; idx < total; idx += stride){
    float2 f = __half22float2(X2[idx]);
    s0 += f.x; q0 += f.x*f.x; s1 += f.y; q1 += f.y*f.y;
  }
  s0m[t]=s0; s1m[t]=s1; q0m[t]=q0; q1m[t]=q1;
  __syncthreads();
  if (t < 64){
    float a0 = s0m[t]+s0m[t+64]+s0m[t+128]+s0m[t+192];
    float a1 = s1m[t]+s1m[t+64]+s1m[t+128]+s1m[t+192];
    float b0 = q0m[t]+q0m[t+64]+q0m[t+128]+q0m[t+192];
    float b1 = q1m[t]+q1m[t+64]+q1m[t+128]+q1m[t+192];
    atomicAdd(&S[2*t],   a0); atomicAdd(&S[2*t+1], a1);
    atomicAdd(&Q[2*t],   b0); atomicAdd(&Q[2*t+1], b1);
  }
}
__global__ void bnparam(const float* __restrict__ S, const float* __restrict__ Q,
                        const float* __restrict__ g, const float* __restrict__ be,
                        float* __restrict__ sc, float* __restrict__ sh){
  int c = threadIdx.x;
  float mean = S[c] / (float)N_NODES;
  float var  = fmaxf(Q[c]/(float)N_NODES - mean*mean, 0.f);
  float scale = g[c]*rsqrtf(var + EPSBN);
  sc[c] = scale;
  sh[c] = be[c] - mean*scale;
}

// ============ pooling (fused BN+ReLU), 4 blocks per graph ============
__global__ void bounds_kernel(const int* __restrict__ batch, int* __restrict__ start){
  int i = blockIdx.x*256 + threadIdx.x;
  if (i >= N_NODES) return;
  int b = batch[i];
  int p = (i == 0) ? -1 : batch[i-1];
  for (int g = p+1; g <= b; ++g) start[g] = i;
  if (i == N_NODES-1)
    for (int g = b+1; g <= NGRAPH; ++g) start[g] = N_NODES;
}
__global__ void pool_h(const __half* __restrict__ Bh, const int* __restrict__ start,
                       const float* __restrict__ sc, const float* __restrict__ sh,
                       float* __restrict__ Pq){
  int g = blockIdx.x >> 2, q = blockIdx.x & 3, f = threadIdx.x;
  int s0 = start[g], len = start[g+1] - s0;
  int n0 = s0 + (len*q)/4, n1 = s0 + (len*(q+1))/4;
  float scl = sc[f], shf = sh[f];
  float acc = 0.f;
  for (int n = n0; n < n1; ++n)
    acc += fmaxf(__half2float(Bh[(long)n*128 + f])*scl + shf, 0.f);
  Pq[(long)blockIdx.x*128 + f] = acc;
}

// ============ MLP head ============
__global__ void final_kernel(const float* __restrict__ Pq, const int* __restrict__ start,
                             const float* __restrict__ fw1, const float* __restrict__ fb1,
                             const float* __restrict__ fw2, const float* __restrict__ fb2,
                             float* __restrict__ out){
  __shared__ float p[128];
  __shared__ float red[2];
  int g = blockIdx.x, t = threadIdx.x;
  float cnt = fmaxf((float)(start[g+1] - start[g]), 1.f);
  float sum = Pq[(long)(g*4+0)*128+t] + Pq[(long)(g*4+1)*128+t]
            + Pq[(long)(g*4+2)*128+t] + Pq[(long)(g*4+3)*128+t];
  p[t] = sum / cnt;
  __syncthreads();
  float acc = fb1[t];
  for (int k = 0; k < 128; ++k) acc += p[k]*fw1[k*128 + t];
  float z = fmaxf(acc, 0.f) * fw2[t];
  for (int off = 32; off; off >>= 1) z += __shfl_down(z, off);
  if ((t & 63) == 0) red[t >> 6] = z;
  __syncthreads();
  if (t == 0) out[g] = red[0] + red[1] + fb2[0];
}

extern "C" void kernel_launch(void* const* d_in, const int* in_sizes, int n_in,
                              void* d_out, int out_size, void* d_ws, size_t ws_size,
                              hipStream_t stream){
  const float* x    = (const float*)d_in[0];
  const int*   ei   = (const int*)d_in[1];
  const int*   batch= (const int*)d_in[2];
  const float* W1   = (const float*)d_in[3];
  const float* g1   = (const float*)d_in[5];
  const float* be1  = (const float*)d_in[6];
  const float* Wg   = (const float*)d_in[7];
  const float* asr  = (const float*)d_in[8];
  const float* adt  = (const float*)d_in[9];
  const float* g2   = (const float*)d_in[11];
  const float* be2  = (const float*)d_in[12];
  const float* W3   = (const float*)d_in[13];
  const float* g3   = (const float*)d_in[15];
  const float* be3  = (const float*)d_in[16];
  const float* fw1  = (const float*)d_in[17];
  const float* fb1  = (const float*)d_in[18];
  const float* fw2  = (const float*)d_in[19];
  const float* fb2  = (const float*)d_in[20];
  float* out = (float*)d_out;

  const long NH = (long)N_NODES*HDIM;          // 6.4M
  __half* Ah    = (__half*)d_ws;               // [N,H] fp16 (gemm out)
  __half* Bh    = Ah + NH;                     // [N,H] fp16 (agg out)
  float* dis    = (float*)(Bh + NH);           // [N]
  float* al_s   = dis + N_NODES;               // [N]
  float* al_d   = al_s + N_NODES;              // [N]
  float* Pq     = al_d + N_NODES;              // [G*4,H]
  float* sc     = Pq + (long)NGRAPH*4*HDIM;    // [128]
  float* sh     = sc + HDIM;                   // [128]
  int* deg_i    = (int*)(sh + HDIM);           // [N]   } zeroed
  int* fill     = deg_i + N_NODES;             // [N]   } zeroed
  float* stats  = (float*)(fill + N_NODES);    // [768] } zeroed
  int* rowp     = (int*)(stats + 768);         // [N]
  int* colx     = rowp + N_NODES;              // [E]
  int* start    = colx + N_EDGES;              // [G+1]
  int* part     = start + NGRAPH + 1;          // [256]

  hipMemsetAsync(deg_i, 0, (size_t)(2*N_NODES + 768) * sizeof(int), stream);

  const int TB = 256;
  const int gE  = (N_EDGES + TB - 1)/TB;       // 2344
  const int gN  = (N_NODES + TB - 1)/TB;       // 196
  const int gG  = N_NODES / 16;                // 3125
  const int gAgg= N_NODES / 4;                 // 12500 (1 wave per node)

  const __half2* Ah2 = (const __half2*)Ah;
  __half2* Bh2w = (__half2*)Bh;
  const __half2* Bh2 = (const __half2*)Bh;

  // ---- CSR build ----
  deg_kernel<<<gE, TB, 0, stream>>>(ei, deg_i);
  dis_kernel<<<gN, TB, 0, stream>>>(deg_i, dis);
  scan_partial<<<SCAN_B, TB, 0, stream>>>(deg_i, part);
  scan_offsets<<<1, TB, 0, stream>>>(part);
  scan_final<<<SCAN_B, TB, 0, stream>>>(deg_i, part, rowp);
  csr_scatter<<<gE, TB, 0, stream>>>(ei, rowp, fill, colx);
  bounds_kernel<<<gN, TB, 0, stream>>>(batch, start);

  // ---- layer 1: GCN ----
  gemm_f32<<<gG, TB, 0, stream>>>(x, W1, Ah);
  gcn_agg<<<gAgg, TB, 0, stream>>>(Ah2, dis, rowp, deg_i, colx, Bh2w);
  stats_h<<<512, TB, 0, stream>>>(Bh2, stats + 0, stats + 128);
  bnparam<<<1, 128, 0, stream>>>(stats + 0, stats + 128, g1, be1, sc, sh);

  // ---- layer 2: GAT (BN of layer1 fused into gemm load; att fused into epilogue) ----
  gemm_h<<<gG, TB, 0, stream>>>(Bh, Wg, sc, sh, Ah, al_s, al_d, asr, adt);
  gat_agg<<<gAgg, TB, 0, stream>>>(Ah2, al_s, al_d, rowp, deg_i, colx, Bh2w);
  stats_h<<<512, TB, 0, stream>>>(Bh2, stats + 256, stats + 384);
  bnparam<<<1, 128, 0, stream>>>(stats + 256, stats + 384, g2, be2, sc, sh);

  // ---- layer 3: GCN ----
  gemm_h<<<gG, TB, 0, stream>>>(Bh, W3, sc, sh, Ah, nullptr, nullptr, nullptr, nullptr);
  gcn_agg<<<gAgg, TB, 0, stream>>>(Ah2, dis, rowp, deg_i, colx, Bh2w);
  stats_h<<<512, TB, 0, stream>>>(Bh2, stats + 512, stats + 640);
  bnparam<<<1, 128, 0, stream>>>(stats + 512, stats + 640, g3, be3, sc, sh);

  // ---- pool (fused BN+ReLU) + MLP head ----
  pool_h<<<NGRAPH*4, 128, 0, stream>>>(Bh, start, sc, sh, Pq);
  final_kernel<<<NGRAPH, 128, 0, stream>>>(Pq, start, fw1, fb1, fw2, fb2, out);
}

// Round 4
// 521.762 us; speedup vs baseline: 2.9290x; 1.1750x over previous
//
#include <hip/hip_runtime.h>
#include <hip/hip_fp16.h>
#include <cstdint>

#define N_NODES 50000
#define N_EDGES 600000
#define HDIM    128
#define NGRAPH  256
#define EPSBN   1e-5f
#define NEG     0.2f
#define SCAN_B  196   // ceil(50000/256)

__device__ __forceinline__ float lrelu(float v){ return v > 0.f ? v : NEG*v; }

typedef _Float16 f16x8 __attribute__((ext_vector_type(8)));
typedef float    f32x4 __attribute__((ext_vector_type(4)));

// ============ weight transpose+convert: Wt[n][k] = (half)W[k][n] ============
__global__ void wt_conv(const float* __restrict__ W1, const float* __restrict__ Wg,
                        const float* __restrict__ W3, __half* __restrict__ Wt1,
                        __half* __restrict__ Wtg, __half* __restrict__ Wt3){
  int b = blockIdx.x;
  const float* W = (b < 64) ? W1 : (b < 128 ? Wg : W3);
  __half*     Wt = (b < 64) ? Wt1 : (b < 128 ? Wtg : Wt3);
  int idx = (b & 63)*256 + threadIdx.x;     // 0..16383
  int k = idx >> 7, n = idx & 127;
  Wt[n*128 + k] = __float2half(W[idx]);
}

// ============ MFMA GEMM: Y[N,128] = act(X)[N,128] @ W[128,128], fp16 out ====
// One wave = 16 rows x 128 cols (8 acc tiles of 16x16, K-loop of 4 x K=32).
// No LDS. A-frag: contiguous 16B load per lane (row-major X).
// B-frag: contiguous 16B load per lane from transposed Wt[n][k].
// BN+ReLU optionally fused into the A-fragment (per-k scale/shift).
template<bool BN, bool F32IN>
__global__ __launch_bounds__(256) void gemm_mfma(const void* __restrict__ Xv,
    const __half* __restrict__ Wt, const float* __restrict__ sc,
    const float* __restrict__ sh, __half* __restrict__ Yh){
  const int t    = threadIdx.x;
  const int wave = t >> 6, lane = t & 63;
  const int q    = lane >> 4, c16 = lane & 15;
  const int m0   = blockIdx.x*64 + wave*16;
  int arow = m0 + c16; if (arow > N_NODES-1) arow = N_NODES-1;  // tail clamp

  f32x4 acc[8];
#pragma unroll
  for (int i = 0; i < 8; ++i) acc[i] = (f32x4){0.f,0.f,0.f,0.f};

  const f16x8* Wt8 = (const f16x8*)Wt;       // row n = 16 groups of 8 halves

#pragma unroll
  for (int kc = 0; kc < 4; ++kc){
    const int kof = kc*32 + q*8;             // this lane's 8 k-indices
    f16x8 a;
    if (F32IN){
      const float* xp = (const float*)Xv + (long)arow*128 + kof;
      float4 x0 = *(const float4*)xp;
      float4 x1 = *(const float4*)(xp + 4);
      a[0]=(_Float16)x0.x; a[1]=(_Float16)x0.y; a[2]=(_Float16)x0.z; a[3]=(_Float16)x0.w;
      a[4]=(_Float16)x1.x; a[5]=(_Float16)x1.y; a[6]=(_Float16)x1.z; a[7]=(_Float16)x1.w;
    } else {
      f16x8 raw = *(const f16x8*)((const _Float16*)Xv + (long)arow*128 + kof);
      if (BN){
        float4 s0 = *(const float4*)(sc + kof), s1 = *(const float4*)(sc + kof + 4);
        float4 h0 = *(const float4*)(sh + kof), h1 = *(const float4*)(sh + kof + 4);
        a[0] = (_Float16)fmaxf((float)raw[0]*s0.x + h0.x, 0.f);
        a[1] = (_Float16)fmaxf((float)raw[1]*s0.y + h0.y, 0.f);
        a[2] = (_Float16)fmaxf((float)raw[2]*s0.z + h0.z, 0.f);
        a[3] = (_Float16)fmaxf((float)raw[3]*s0.w + h0.w, 0.f);
        a[4] = (_Float16)fmaxf((float)raw[4]*s1.x + h1.x, 0.f);
        a[5] = (_Float16)fmaxf((float)raw[5]*s1.y + h1.y, 0.f);
        a[6] = (_Float16)fmaxf((float)raw[6]*s1.z + h1.z, 0.f);
        a[7] = (_Float16)fmaxf((float)raw[7]*s1.w + h1.w, 0.f);
      } else {
        a = raw;
      }
    }
#pragma unroll
    for (int nt = 0; nt < 8; ++nt){
      f16x8 b = Wt8[(nt*16 + c16)*16 + kc*4 + q];   // Wt[n0+c16][kof..kof+7]
      acc[nt] = __builtin_amdgcn_mfma_f32_16x16x32_f16(a, b, acc[nt], 0, 0, 0);
    }
  }
  // C/D layout: col = lane&15, row = quad*4 + reg
#pragma unroll
  for (int r = 0; r < 4; ++r){
    int row = m0 + q*4 + r;
    if (row < N_NODES){
      __half* yp = Yh + (long)row*128 + c16;
#pragma unroll
      for (int nt = 0; nt < 8; ++nt)
        yp[nt*16] = __float2half(acc[nt][r]);
    }
  }
}

// ============ CSR build ============
__global__ void deg_kernel(const int* __restrict__ ei, int* __restrict__ degi){
  int e = blockIdx.x*256 + threadIdx.x;
  if (e < N_EDGES) atomicAdd(&degi[ei[N_EDGES + e]], 1);
}
__global__ void dis_kernel(const int* __restrict__ degi, float* __restrict__ dis){
  int i = blockIdx.x*256 + threadIdx.x;
  if (i < N_NODES) dis[i] = rsqrtf((float)degi[i] + 1.f);
}
__global__ void scan_partial(const int* __restrict__ degi, int* __restrict__ part){
  __shared__ int sm[256];
  int t = threadIdx.x; int i = blockIdx.x*256 + t;
  sm[t] = (i < N_NODES) ? degi[i] : 0;
  __syncthreads();
  for (int off = 128; off; off >>= 1){
    if (t < off) sm[t] += sm[t + off];
    __syncthreads();
  }
  if (t == 0) part[blockIdx.x] = sm[0];
}
__global__ void scan_offsets(int* part){
  __shared__ int sm[256];
  int t = threadIdx.x;
  int v = (t < SCAN_B) ? part[t] : 0;
  sm[t] = v; __syncthreads();
  for (int off = 1; off < 256; off <<= 1){
    int add = (t >= off) ? sm[t - off] : 0;
    __syncthreads();
    sm[t] += add; __syncthreads();
  }
  if (t < SCAN_B) part[t] = sm[t] - v;
}
__global__ void scan_final(const int* __restrict__ degi, const int* __restrict__ part,
                           int* __restrict__ rowp){
  __shared__ int sm[256];
  int t = threadIdx.x; int i = blockIdx.x*256 + t;
  int v = (i < N_NODES) ? degi[i] : 0;
  sm[t] = v; __syncthreads();
  for (int off = 1; off < 256; off <<= 1){
    int add = (t >= off) ? sm[t - off] : 0;
    __syncthreads();
    sm[t] += add; __syncthreads();
  }
  if (i < N_NODES) rowp[i] = part[blockIdx.x] + sm[t] - v;
}
__global__ void csr_scatter(const int* __restrict__ ei, const int* __restrict__ rowp,
                            int* __restrict__ fill, int* __restrict__ colx){
  int e = blockIdx.x*256 + threadIdx.x;
  if (e >= N_EDGES) return;
  int s = ei[e], d = ei[N_EDGES + e];
  int pos = rowp[d] + atomicAdd(&fill[d], 1);
  colx[pos] = s;
}

// ============ GCN aggregation: wave per node, lane-broadcast gather ============
__global__ __launch_bounds__(256) void gcn_agg(const __half2* __restrict__ Ah2,
    const float* __restrict__ dis, const int* __restrict__ rowp,
    const int* __restrict__ degi, const int* __restrict__ colx,
    __half2* __restrict__ Bh2){
  const int n = blockIdx.x*4 + (threadIdx.x >> 6);
  const int lane = threadIdx.x & 63;
  const float dn = dis[n];
  float2 self = __half22float2(Ah2[n*64 + lane]);
  float accx = self.x * dn, accy = self.y * dn;
  const int e0 = rowp[n], cnt = degi[n];
  for (int base = 0; base < cnt; base += 64){
    int idx = base + lane;
    int s = 0; float w = 0.f;
    if (idx < cnt){ s = colx[e0 + idx]; w = dis[s]; }
    int lim = min(64, cnt - base);
    for (int j = 0; j < lim; ++j){
      int   sj = __shfl(s, j);
      float wj = __shfl(w, j);
      float2 f = __half22float2(Ah2[sj*64 + lane]);
      accx += wj * f.x; accy += wj * f.y;
    }
  }
  Bh2[n*64 + lane] = __floats2half2_rn(accx * dn, accy * dn);
}

// ============ GAT attention logits (one wave per node) ============
__global__ void att_h(const __half2* __restrict__ Ah2,
                      const float* __restrict__ asr, const float* __restrict__ adt,
                      float* __restrict__ al_s, float* __restrict__ al_d){
  int n = blockIdx.x*4 + (threadIdx.x >> 6);
  int lane = threadIdx.x & 63;
  float2 f = __half22float2(Ah2[n*64 + lane]);
  float2 a = *(const float2*)(asr + 2*lane);
  float2 b = *(const float2*)(adt + 2*lane);
  float s = f.x*a.x + f.y*a.y;
  float d = f.x*b.x + f.y*b.y;
#pragma unroll
  for (int off = 32; off; off >>= 1){
    s += __shfl_xor(s, off);
    d += __shfl_xor(d, off);
  }
  if (lane == 0){ al_s[n] = s; al_d[n] = d; }
}

// ============ GAT aggregation: wave per node, 1 exp/edge ============
__global__ __launch_bounds__(256) void gat_agg(const __half2* __restrict__ Ah2,
    const float* __restrict__ al_s, const float* __restrict__ al_d,
    const int* __restrict__ rowp, const int* __restrict__ degi,
    const int* __restrict__ colx, __half2* __restrict__ Bh2){
  const int n = blockIdx.x*4 + (threadIdx.x >> 6);
  const int lane = threadIdx.x & 63;
  const float adn = al_d[n];
  const float lself = lrelu(al_s[n] + adn);
  const int e0 = rowp[n], cnt = degi[n];
  float m = lself;
  for (int base = 0; base < cnt; base += 64){
    int idx = base + lane;
    if (idx < cnt) m = fmaxf(m, lrelu(al_s[colx[e0 + idx]] + adn));
  }
#pragma unroll
  for (int off = 32; off; off >>= 1) m = fmaxf(m, __shfl_xor(m, off));
  float exs = __expf(lself - m);
  float2 self = __half22float2(Ah2[n*64 + lane]);
  float accx = exs*self.x, accy = exs*self.y;
  float dpart = 0.f;
  for (int base = 0; base < cnt; base += 64){
    int idx = base + lane;
    int s = 0; float w = 0.f;
    if (idx < cnt){ s = colx[e0 + idx]; w = __expf(lrelu(al_s[s] + adn) - m); }
    dpart += w;
    int lim = min(64, cnt - base);
    for (int j = 0; j < lim; ++j){
      int   sj = __shfl(s, j);
      float wj = __shfl(w, j);
      float2 f = __half22float2(Ah2[sj*64 + lane]);
      accx += wj * f.x; accy += wj * f.y;
    }
  }
#pragma unroll
  for (int off = 32; off; off >>= 1) dpart += __shfl_xor(dpart, off);
  float r = 1.f / (dpart + exs);
  Bh2[n*64 + lane] = __floats2half2_rn(accx * r, accy * r);
}

// ============ BN stats over fp16 tensor ============
__global__ void stats_h(const __half2* __restrict__ X2,
                        float* __restrict__ S, float* __restrict__ Q){
  __shared__ float s0m[256], s1m[256], q0m[256], q1m[256];
  int t = threadIdx.x;
  float s0=0,s1=0,q0=0,q1=0;
  int stride = gridDim.x*256;
  const int total = N_NODES*64;
  for (int idx = blockIdx.x*256 + t; idx < total; idx += stride){
    float2 f = __half22float2(X2[idx]);
    s0 += f.x; q0 += f.x*f.x; s1 += f.y; q1 += f.y*f.y;
  }
  s0m[t]=s0; s1m[t]=s1; q0m[t]=q0; q1m[t]=q1;
  __syncthreads();
  if (t < 64){
    float a0 = s0m[t]+s0m[t+64]+s0m[t+128]+s0m[t+192];
    float a1 = s1m[t]+s1m[t+64]+s1m[t+128]+s1m[t+192];
    float b0 = q0m[t]+q0m[t+64]+q0m[t+128]+q0m[t+192];
    float b1 = q1m[t]+q1m[t+64]+q1m[t+128]+q1m[t+192];
    atomicAdd(&S[2*t],   a0); atomicAdd(&S[2*t+1], a1);
    atomicAdd(&Q[2*t],   b0); atomicAdd(&Q[2*t+1], b1);
  }
}
__global__ void bnparam(const float* __restrict__ S, const float* __restrict__ Q,
                        const float* __restrict__ g, const float* __restrict__ be,
                        float* __restrict__ sc, float* __restrict__ sh){
  int c = threadIdx.x;
  float mean = S[c] / (float)N_NODES;
  float var  = fmaxf(Q[c]/(float)N_NODES - mean*mean, 0.f);
  float scale = g[c]*rsqrtf(var + EPSBN);
  sc[c] = scale;
  sh[c] = be[c] - mean*scale;
}

// ============ pooling (fused BN+ReLU), 4 blocks per graph ============
__global__ void bounds_kernel(const int* __restrict__ batch, int* __restrict__ start){
  int i = blockIdx.x*256 + threadIdx.x;
  if (i >= N_NODES) return;
  int b = batch[i];
  int p = (i == 0) ? -1 : batch[i-1];
  for (int g = p+1; g <= b; ++g) start[g] = i;
  if (i == N_NODES-1)
    for (int g = b+1; g <= NGRAPH; ++g) start[g] = N_NODES;
}
__global__ void pool_h(const __half* __restrict__ Bh, const int* __restrict__ start,
                       const float* __restrict__ sc, const float* __restrict__ sh,
                       float* __restrict__ Pq){
  int g = blockIdx.x >> 2, q = blockIdx.x & 3, f = threadIdx.x;
  int s0 = start[g], len = start[g+1] - s0;
  int n0 = s0 + (len*q)/4, n1 = s0 + (len*(q+1))/4;
  float scl = sc[f], shf = sh[f];
  float acc = 0.f;
  for (int n = n0; n < n1; ++n)
    acc += fmaxf(__half2float(Bh[(long)n*128 + f])*scl + shf, 0.f);
  Pq[(long)blockIdx.x*128 + f] = acc;
}

// ============ MLP head ============
__global__ void final_kernel(const float* __restrict__ Pq, const int* __restrict__ start,
                             const float* __restrict__ fw1, const float* __restrict__ fb1,
                             const float* __restrict__ fw2, const float* __restrict__ fb2,
                             float* __restrict__ out){
  __shared__ float p[128];
  __shared__ float red[2];
  int g = blockIdx.x, t = threadIdx.x;
  float cnt = fmaxf((float)(start[g+1] - start[g]), 1.f);
  float sum = Pq[(long)(g*4+0)*128+t] + Pq[(long)(g*4+1)*128+t]
            + Pq[(long)(g*4+2)*128+t] + Pq[(long)(g*4+3)*128+t];
  p[t] = sum / cnt;
  __syncthreads();
  float acc = fb1[t];
  for (int k = 0; k < 128; ++k) acc += p[k]*fw1[k*128 + t];
  float z = fmaxf(acc, 0.f) * fw2[t];
  for (int off = 32; off; off >>= 1) z += __shfl_down(z, off);
  if ((t & 63) == 0) red[t >> 6] = z;
  __syncthreads();
  if (t == 0) out[g] = red[0] + red[1] + fb2[0];
}

extern "C" void kernel_launch(void* const* d_in, const int* in_sizes, int n_in,
                              void* d_out, int out_size, void* d_ws, size_t ws_size,
                              hipStream_t stream){
  const float* x    = (const float*)d_in[0];
  const int*   ei   = (const int*)d_in[1];
  const int*   batch= (const int*)d_in[2];
  const float* W1   = (const float*)d_in[3];
  const float* g1   = (const float*)d_in[5];
  const float* be1  = (const float*)d_in[6];
  const float* Wg   = (const float*)d_in[7];
  const float* asr  = (const float*)d_in[8];
  const float* adt  = (const float*)d_in[9];
  const float* g2   = (const float*)d_in[11];
  const float* be2  = (const float*)d_in[12];
  const float* W3   = (const float*)d_in[13];
  const float* g3   = (const float*)d_in[15];
  const float* be3  = (const float*)d_in[16];
  const float* fw1  = (const float*)d_in[17];
  const float* fb1  = (const float*)d_in[18];
  const float* fw2  = (const float*)d_in[19];
  const float* fb2  = (const float*)d_in[20];
  float* out = (float*)d_out;

  const long NH = (long)N_NODES*HDIM;          // 6.4M
  __half* Ah    = (__half*)d_ws;               // [N,H] fp16 (gemm out)
  __half* Bh    = Ah + NH;                     // [N,H] fp16 (agg out)
  __half* Wt1   = Bh + NH;                     // [128,128] fp16 transposed
  __half* Wtg   = Wt1 + 16384;
  __half* Wt3   = Wtg + 16384;
  float* dis    = (float*)(Wt3 + 16384);       // [N]
  float* al_s   = dis + N_NODES;               // [N]
  float* al_d   = al_s + N_NODES;              // [N]
  float* Pq     = al_d + N_NODES;              // [G*4,H]
  float* sc     = Pq + (long)NGRAPH*4*HDIM;    // [128]
  float* sh     = sc + HDIM;                   // [128]
  int* deg_i    = (int*)(sh + HDIM);           // [N]   } zeroed
  int* fill     = deg_i + N_NODES;             // [N]   } zeroed
  float* stats  = (float*)(fill + N_NODES);    // [768] } zeroed
  int* rowp     = (int*)(stats + 768);         // [N]
  int* colx     = rowp + N_NODES;              // [E]
  int* start    = colx + N_EDGES;              // [G+1]
  int* part     = start + NGRAPH + 1;          // [256]

  hipMemsetAsync(deg_i, 0, (size_t)(2*N_NODES + 768) * sizeof(int), stream);

  const int TB = 256;
  const int gE  = (N_EDGES + TB - 1)/TB;       // 2344
  const int gN  = (N_NODES + TB - 1)/TB;       // 196
  const int gMM = (N_NODES + 63)/64;           // 782 (MFMA gemm, 64 rows/block)
  const int gAgg= N_NODES / 4;                 // 12500 (1 wave per node)

  const __half2* Ah2 = (const __half2*)Ah;
  __half2* Bh2w = (__half2*)Bh;
  const __half2* Bh2 = (const __half2*)Bh;

  // ---- weight prep + CSR build ----
  wt_conv<<<192, TB, 0, stream>>>(W1, Wg, W3, Wt1, Wtg, Wt3);
  deg_kernel<<<gE, TB, 0, stream>>>(ei, deg_i);
  dis_kernel<<<gN, TB, 0, stream>>>(deg_i, dis);
  scan_partial<<<SCAN_B, TB, 0, stream>>>(deg_i, part);
  scan_offsets<<<1, TB, 0, stream>>>(part);
  scan_final<<<SCAN_B, TB, 0, stream>>>(deg_i, part, rowp);
  csr_scatter<<<gE, TB, 0, stream>>>(ei, rowp, fill, colx);
  bounds_kernel<<<gN, TB, 0, stream>>>(batch, start);

  // ---- layer 1: GCN ----
  gemm_mfma<false,true><<<gMM, TB, 0, stream>>>(x, Wt1, nullptr, nullptr, Ah);
  gcn_agg<<<gAgg, TB, 0, stream>>>(Ah2, dis, rowp, deg_i, colx, Bh2w);
  stats_h<<<512, TB, 0, stream>>>(Bh2, stats + 0, stats + 128);
  bnparam<<<1, 128, 0, stream>>>(stats + 0, stats + 128, g1, be1, sc, sh);

  // ---- layer 2: GAT (BN of layer 1 fused into gemm A-frag load) ----
  gemm_mfma<true,false><<<gMM, TB, 0, stream>>>(Bh, Wtg, sc, sh, Ah);
  att_h<<<gAgg, TB, 0, stream>>>(Ah2, asr, adt, al_s, al_d);
  gat_agg<<<gAgg, TB, 0, stream>>>(Ah2, al_s, al_d, rowp, deg_i, colx, Bh2w);
  stats_h<<<512, TB, 0, stream>>>(Bh2, stats + 256, stats + 384);
  bnparam<<<1, 128, 0, stream>>>(stats + 256, stats + 384, g2, be2, sc, sh);

  // ---- layer 3: GCN ----
  gemm_mfma<true,false><<<gMM, TB, 0, stream>>>(Bh, Wt3, sc, sh, Ah);
  gcn_agg<<<gAgg, TB, 0, stream>>>(Ah2, dis, rowp, deg_i, colx, Bh2w);
  stats_h<<<512, TB, 0, stream>>>(Bh2, stats + 512, stats + 640);
  bnparam<<<1, 128, 0, stream>>>(stats + 512, stats + 640, g3, be3, sc, sh);

  // ---- pool (fused BN+ReLU) + MLP head ----
  pool_h<<<NGRAPH*4, 128, 0, stream>>>(Bh, start, sc, sh, Pq);
  final_kernel<<<NGRAPH, 128, 0, stream>>>(Pq, start, fw1, fb1, fw2, fb2, out);
}

// Round 5
// 470.240 us; speedup vs baseline: 3.2499x; 1.1096x over previous
//
#include <hip/hip_runtime.h>
#include <hip/hip_fp16.h>
#include <cstdint>

#define N_NODES 50000
#define N_EDGES 600000
#define HDIM    128
#define NGRAPH  256
#define EPSBN   1e-5f
#define NEG     0.2f
#define SCAN_B  196   // ceil(50000/256)

__device__ __forceinline__ float lrelu(float v){ return v > 0.f ? v : NEG*v; }

typedef _Float16 f16x8 __attribute__((ext_vector_type(8)));
typedef float    f32x4 __attribute__((ext_vector_type(4)));

// ============ weight transpose+convert: Wt[n][k] = (half)W[k][n] ============
__global__ void wt_conv(const float* __restrict__ W1, const float* __restrict__ Wg,
                        const float* __restrict__ W3, __half* __restrict__ Wt1,
                        __half* __restrict__ Wtg, __half* __restrict__ Wt3){
  int b = blockIdx.x;
  const float* W = (b < 64) ? W1 : (b < 128 ? Wg : W3);
  __half*     Wt = (b < 64) ? Wt1 : (b < 128 ? Wtg : Wt3);
  int idx = (b & 63)*256 + threadIdx.x;     // 0..16383
  int k = idx >> 7, n = idx & 127;
  Wt[n*128 + k] = __float2half(W[idx]);
}

// ============ MFMA GEMM (swapped operands): Y = act(X) @ W, fp16 out ============
// mfma(wt_frag, x_frag): D[row=n(quad*4+reg)][col=m(lane&15)] -> lane holds
// row m = lane&15, cols nt*16 + q*4 + r  => contiguous 8B stores per tile.
// Optional fused BN+ReLU on X fragment; optional attention-logit epilogue.
template<bool BN, bool F32IN, bool ATT>
__global__ __launch_bounds__(256) void gemm_mfma(const void* __restrict__ Xv,
    const __half* __restrict__ Wt, const float* __restrict__ sc,
    const float* __restrict__ sh, __half* __restrict__ Yh,
    const float* __restrict__ asr, const float* __restrict__ adt,
    float* __restrict__ al_s, float* __restrict__ al_d){
  const int t    = threadIdx.x;
  const int wave = t >> 6, lane = t & 63;
  const int q    = lane >> 4, c16 = lane & 15;
  const int m0   = blockIdx.x*64 + wave*16;
  const int row  = m0 + c16;
  const int arow = (row > N_NODES-1) ? N_NODES-1 : row;   // tail clamp (reads only)

  f32x4 acc[8];
#pragma unroll
  for (int i = 0; i < 8; ++i) acc[i] = (f32x4){0.f,0.f,0.f,0.f};

  const f16x8* Wt8 = (const f16x8*)Wt;

#pragma unroll
  for (int kc = 0; kc < 4; ++kc){
    const int kof = kc*32 + q*8;
    f16x8 a;
    if (F32IN){
      const float* xp = (const float*)Xv + (long)arow*128 + kof;
      float4 x0 = *(const float4*)xp;
      float4 x1 = *(const float4*)(xp + 4);
      a[0]=(_Float16)x0.x; a[1]=(_Float16)x0.y; a[2]=(_Float16)x0.z; a[3]=(_Float16)x0.w;
      a[4]=(_Float16)x1.x; a[5]=(_Float16)x1.y; a[6]=(_Float16)x1.z; a[7]=(_Float16)x1.w;
    } else {
      f16x8 raw = *(const f16x8*)((const _Float16*)Xv + (long)arow*128 + kof);
      if (BN){
        float4 s0 = *(const float4*)(sc + kof), s1 = *(const float4*)(sc + kof + 4);
        float4 h0 = *(const float4*)(sh + kof), h1 = *(const float4*)(sh + kof + 4);
        a[0] = (_Float16)fmaxf((float)raw[0]*s0.x + h0.x, 0.f);
        a[1] = (_Float16)fmaxf((float)raw[1]*s0.y + h0.y, 0.f);
        a[2] = (_Float16)fmaxf((float)raw[2]*s0.z + h0.z, 0.f);
        a[3] = (_Float16)fmaxf((float)raw[3]*s0.w + h0.w, 0.f);
        a[4] = (_Float16)fmaxf((float)raw[4]*s1.x + h1.x, 0.f);
        a[5] = (_Float16)fmaxf((float)raw[5]*s1.y + h1.y, 0.f);
        a[6] = (_Float16)fmaxf((float)raw[6]*s1.z + h1.z, 0.f);
        a[7] = (_Float16)fmaxf((float)raw[7]*s1.w + h1.w, 0.f);
      } else {
        a = raw;
      }
    }
#pragma unroll
    for (int nt = 0; nt < 8; ++nt){
      f16x8 b = Wt8[(nt*16 + c16)*16 + kc*4 + q];   // Wt[nt*16+c16][kof..+8)
      acc[nt] = __builtin_amdgcn_mfma_f32_16x16x32_f16(b, a, acc[nt], 0, 0, 0);
    }
  }
  if (row < N_NODES){
    __half* yp = Yh + (long)row*128 + q*4;   // + nt*16 per tile
#pragma unroll
    for (int nt = 0; nt < 8; ++nt){
      union { uint2 u; __half2 h[2]; } pk;
      pk.h[0] = __floats2half2_rn(acc[nt][0], acc[nt][1]);
      pk.h[1] = __floats2half2_rn(acc[nt][2], acc[nt][3]);
      *(uint2*)(yp + nt*16) = pk.u;
    }
  }
  if (ATT){
    float s = 0.f, d = 0.f;
#pragma unroll
    for (int nt = 0; nt < 8; ++nt){
      float4 av = *(const float4*)(asr + nt*16 + q*4);
      float4 bv = *(const float4*)(adt + nt*16 + q*4);
      s += acc[nt][0]*av.x + acc[nt][1]*av.y + acc[nt][2]*av.z + acc[nt][3]*av.w;
      d += acc[nt][0]*bv.x + acc[nt][1]*bv.y + acc[nt][2]*bv.z + acc[nt][3]*bv.w;
    }
    s += __shfl_xor(s, 16); s += __shfl_xor(s, 32);
    d += __shfl_xor(d, 16); d += __shfl_xor(d, 32);
    if (q == 0 && row < N_NODES){ al_s[row] = s; al_d[row] = d; }
  }
}

// ============ CSR build ============
__global__ void deg_kernel(const int* __restrict__ ei, int* __restrict__ degi){
  int e = blockIdx.x*256 + threadIdx.x;
  if (e < N_EDGES) atomicAdd(&degi[ei[N_EDGES + e]], 1);
}
__global__ void dis_kernel(const int* __restrict__ degi, float* __restrict__ dis){
  int i = blockIdx.x*256 + threadIdx.x;
  if (i < N_NODES) dis[i] = rsqrtf((float)degi[i] + 1.f);
}
__global__ void scan_partial(const int* __restrict__ degi, int* __restrict__ part){
  __shared__ int sm[256];
  int t = threadIdx.x; int i = blockIdx.x*256 + t;
  sm[t] = (i < N_NODES) ? degi[i] : 0;
  __syncthreads();
  for (int off = 128; off; off >>= 1){
    if (t < off) sm[t] += sm[t + off];
    __syncthreads();
  }
  if (t == 0) part[blockIdx.x] = sm[0];
}
__global__ void scan_offsets(int* part){
  __shared__ int sm[256];
  int t = threadIdx.x;
  int v = (t < SCAN_B) ? part[t] : 0;
  sm[t] = v; __syncthreads();
  for (int off = 1; off < 256; off <<= 1){
    int add = (t >= off) ? sm[t - off] : 0;
    __syncthreads();
    sm[t] += add; __syncthreads();
  }
  if (t < SCAN_B) part[t] = sm[t] - v;
}
__global__ void scan_final(const int* __restrict__ degi, const int* __restrict__ part,
                           int* __restrict__ rowp){
  __shared__ int sm[256];
  int t = threadIdx.x; int i = blockIdx.x*256 + t;
  int v = (i < N_NODES) ? degi[i] : 0;
  sm[t] = v; __syncthreads();
  for (int off = 1; off < 256; off <<= 1){
    int add = (t >= off) ? sm[t - off] : 0;
    __syncthreads();
    sm[t] += add; __syncthreads();
  }
  if (i < N_NODES) rowp[i] = part[blockIdx.x] + sm[t] - v;
}
__global__ void csr_scatter(const int* __restrict__ ei, const int* __restrict__ rowp,
                            int* __restrict__ fill, int* __restrict__ colx){
  int e = blockIdx.x*256 + threadIdx.x;
  if (e >= N_EDGES) return;
  int s = ei[e], d = ei[N_EDGES + e];
  int pos = rowp[d] + atomicAdd(&fill[d], 1);
  colx[pos] = s;
}

// ============ GCN aggregation: wave/node, 4 edge-rows per VMEM instr ============
__global__ __launch_bounds__(256) void gcn_agg(const _Float16* __restrict__ Ah,
    const float* __restrict__ dis, const int* __restrict__ rowp,
    const int* __restrict__ degi, const int* __restrict__ colx,
    __half* __restrict__ Bh){
  const int n = blockIdx.x*4 + (threadIdx.x >> 6);
  const int lane = threadIdx.x & 63;
  const int g = lane >> 4, p = lane & 15;
  const float dn = dis[n];
  float acc[8] = {0,0,0,0,0,0,0,0};
  if (g == 0){
    f16x8 self = *(const f16x8*)(Ah + (long)n*128 + p*8);
#pragma unroll
    for (int i = 0; i < 8; ++i) acc[i] = dn * (float)self[i];
  }
  const int e0 = rowp[n], cnt = degi[n];
  for (int base = 0; base < cnt; base += 64){
    int idx = base + lane;
    int s = 0; float w = 0.f;
    if (idx < cnt){ s = colx[e0 + idx]; w = dis[s]; }
    int nit = min(64, cnt - base);
    for (int j = 0; j < nit; j += 4){
      int   sj = __shfl(s, j + g);       // w=0 past cnt -> contributes 0
      float wj = __shfl(w, j + g);
      f16x8 r = *(const f16x8*)(Ah + (long)sj*128 + p*8);
#pragma unroll
      for (int i = 0; i < 8; ++i) acc[i] += wj * (float)r[i];
    }
  }
#pragma unroll
  for (int i = 0; i < 8; ++i){
    acc[i] += __shfl_xor(acc[i], 16);
    acc[i] += __shfl_xor(acc[i], 32);
  }
  if (g == 0){
    union { uint4 u; __half2 h[4]; } pk;
#pragma unroll
    for (int i = 0; i < 4; ++i)
      pk.h[i] = __floats2half2_rn(acc[2*i]*dn, acc[2*i+1]*dn);
    *(uint4*)(Bh + (long)n*128 + p*8) = pk.u;
  }
}

// ============ GAT aggregation: wave/node, 4 edge-rows per VMEM instr ============
__global__ __launch_bounds__(256) void gat_agg(const _Float16* __restrict__ Ah,
    const float* __restrict__ al_s, const float* __restrict__ al_d,
    const int* __restrict__ rowp, const int* __restrict__ degi,
    const int* __restrict__ colx, __half* __restrict__ Bh){
  const int n = blockIdx.x*4 + (threadIdx.x >> 6);
  const int lane = threadIdx.x & 63;
  const int g = lane >> 4, p = lane & 15;
  const float adn = al_d[n];
  const float lself = lrelu(al_s[n] + adn);
  const int e0 = rowp[n], cnt = degi[n];
  // pass 1: segment max
  float m = lself;
  for (int base = 0; base < cnt; base += 64){
    int idx = base + lane;
    if (idx < cnt) m = fmaxf(m, lrelu(al_s[colx[e0 + idx]] + adn));
  }
#pragma unroll
  for (int off = 32; off; off >>= 1) m = fmaxf(m, __shfl_xor(m, off));
  const float exs = __expf(lself - m);
  float acc[8] = {0,0,0,0,0,0,0,0};
  if (g == 0){
    f16x8 self = *(const f16x8*)(Ah + (long)n*128 + p*8);
#pragma unroll
    for (int i = 0; i < 8; ++i) acc[i] = exs * (float)self[i];
  }
  float dpart = 0.f;
  for (int base = 0; base < cnt; base += 64){
    int idx = base + lane;
    int s = 0; float w = 0.f;
    if (idx < cnt){ s = colx[e0 + idx]; w = __expf(lrelu(al_s[s] + adn) - m); }
    dpart += w;
    int nit = min(64, cnt - base);
    for (int j = 0; j < nit; j += 4){
      int   sj = __shfl(s, j + g);
      float wj = __shfl(w, j + g);
      f16x8 r = *(const f16x8*)(Ah + (long)sj*128 + p*8);
#pragma unroll
      for (int i = 0; i < 8; ++i) acc[i] += wj * (float)r[i];
    }
  }
#pragma unroll
  for (int off = 32; off; off >>= 1) dpart += __shfl_xor(dpart, off);
#pragma unroll
  for (int i = 0; i < 8; ++i){
    acc[i] += __shfl_xor(acc[i], 16);
    acc[i] += __shfl_xor(acc[i], 32);
  }
  if (g == 0){
    float rinv = 1.f / (dpart + exs);
    union { uint4 u; __half2 h[4]; } pk;
#pragma unroll
    for (int i = 0; i < 4; ++i)
      pk.h[i] = __floats2half2_rn(acc[2*i]*rinv, acc[2*i+1]*rinv);
    *(uint4*)(Bh + (long)n*128 + p*8) = pk.u;
  }
}

// ============ BN stats over fp16 tensor ============
__global__ void stats_h(const __half2* __restrict__ X2,
                        float* __restrict__ S, float* __restrict__ Q){
  __shared__ float s0m[256], s1m[256], q0m[256], q1m[256];
  int t = threadIdx.x;
  float s0=0,s1=0,q0=0,q1=0;
  int stride = gridDim.x*256;
  const int total = N_NODES*64;
  for (int idx = blockIdx.x*256 + t; idx < total; idx += stride){
    float2 f = __half22float2(X2[idx]);
    s0 += f.x; q0 += f.x*f.x; s1 += f.y; q1 += f.y*f.y;
  }
  s0m[t]=s0; s1m[t]=s1; q0m[t]=q0; q1m[t]=q1;
  __syncthreads();
  if (t < 64){
    float a0 = s0m[t]+s0m[t+64]+s0m[t+128]+s0m[t+192];
    float a1 = s1m[t]+s1m[t+64]+s1m[t+128]+s1m[t+192];
    float b0 = q0m[t]+q0m[t+64]+q0m[t+128]+q0m[t+192];
    float b1 = q1m[t]+q1m[t+64]+q1m[t+128]+q1m[t+192];
    atomicAdd(&S[2*t],   a0); atomicAdd(&S[2*t+1], a1);
    atomicAdd(&Q[2*t],   b0); atomicAdd(&Q[2*t+1], b1);
  }
}
__global__ void bnparam(const float* __restrict__ S, const float* __restrict__ Q,
                        const float* __restrict__ g, const float* __restrict__ be,
                        float* __restrict__ sc, float* __restrict__ sh){
  int c = threadIdx.x;
  float mean = S[c] / (float)N_NODES;
  float var  = fmaxf(Q[c]/(float)N_NODES - mean*mean, 0.f);
  float scale = g[c]*rsqrtf(var + EPSBN);
  sc[c] = scale;
  sh[c] = be[c] - mean*scale;
}

// ============ pooling (fused BN+ReLU), 4 blocks per graph ============
__global__ void bounds_kernel(const int* __restrict__ batch, int* __restrict__ start){
  int i = blockIdx.x*256 + threadIdx.x;
  if (i >= N_NODES) return;
  int b = batch[i];
  int p = (i == 0) ? -1 : batch[i-1];
  for (int g = p+1; g <= b; ++g) start[g] = i;
  if (i == N_NODES-1)
    for (int g = b+1; g <= NGRAPH; ++g) start[g] = N_NODES;
}
__global__ void pool_h(const __half* __restrict__ Bh, const int* __restrict__ start,
                       const float* __restrict__ sc, const float* __restrict__ sh,
                       float* __restrict__ Pq){
  int g = blockIdx.x >> 2, q = blockIdx.x & 3, f = threadIdx.x;
  int s0 = start[g], len = start[g+1] - s0;
  int n0 = s0 + (len*q)/4, n1 = s0 + (len*(q+1))/4;
  float scl = sc[f], shf = sh[f];
  float acc = 0.f;
  for (int n = n0; n < n1; ++n)
    acc += fmaxf(__half2float(Bh[(long)n*128 + f])*scl + shf, 0.f);
  Pq[(long)blockIdx.x*128 + f] = acc;
}

// ============ MLP head ============
__global__ void final_kernel(const float* __restrict__ Pq, const int* __restrict__ start,
                             const float* __restrict__ fw1, const float* __restrict__ fb1,
                             const float* __restrict__ fw2, const float* __restrict__ fb2,
                             float* __restrict__ out){
  __shared__ float p[128];
  __shared__ float red[2];
  int g = blockIdx.x, t = threadIdx.x;
  float cnt = fmaxf((float)(start[g+1] - start[g]), 1.f);
  float sum = Pq[(long)(g*4+0)*128+t] + Pq[(long)(g*4+1)*128+t]
            + Pq[(long)(g*4+2)*128+t] + Pq[(long)(g*4+3)*128+t];
  p[t] = sum / cnt;
  __syncthreads();
  float acc = fb1[t];
  for (int k = 0; k < 128; ++k) acc += p[k]*fw1[k*128 + t];
  float z = fmaxf(acc, 0.f) * fw2[t];
  for (int off = 32; off; off >>= 1) z += __shfl_down(z, off);
  if ((t & 63) == 0) red[t >> 6] = z;
  __syncthreads();
  if (t == 0) out[g] = red[0] + red[1] + fb2[0];
}

extern "C" void kernel_launch(void* const* d_in, const int* in_sizes, int n_in,
                              void* d_out, int out_size, void* d_ws, size_t ws_size,
                              hipStream_t stream){
  const float* x    = (const float*)d_in[0];
  const int*   ei   = (const int*)d_in[1];
  const int*   batch= (const int*)d_in[2];
  const float* W1   = (const float*)d_in[3];
  const float* g1   = (const float*)d_in[5];
  const float* be1  = (const float*)d_in[6];
  const float* Wg   = (const float*)d_in[7];
  const float* asr  = (const float*)d_in[8];
  const float* adt  = (const float*)d_in[9];
  const float* g2   = (const float*)d_in[11];
  const float* be2  = (const float*)d_in[12];
  const float* W3   = (const float*)d_in[13];
  const float* g3   = (const float*)d_in[15];
  const float* be3  = (const float*)d_in[16];
  const float* fw1  = (const float*)d_in[17];
  const float* fb1  = (const float*)d_in[18];
  const float* fw2  = (const float*)d_in[19];
  const float* fb2  = (const float*)d_in[20];
  float* out = (float*)d_out;

  const long NH = (long)N_NODES*HDIM;          // 6.4M
  __half* Ah    = (__half*)d_ws;               // [N,H] fp16 (gemm out)
  __half* Bh    = Ah + NH;                     // [N,H] fp16 (agg out)
  __half* Wt1   = Bh + NH;                     // [128,128] fp16 transposed
  __half* Wtg   = Wt1 + 16384;
  __half* Wt3   = Wtg + 16384;
  float* dis    = (float*)(Wt3 + 16384);       // [N]
  float* al_s   = dis + N_NODES;               // [N]
  float* al_d   = al_s + N_NODES;              // [N]
  float* Pq     = al_d + N_NODES;              // [G*4,H]
  float* sc     = Pq + (long)NGRAPH*4*HDIM;    // [128]
  float* sh     = sc + HDIM;                   // [128]
  int* deg_i    = (int*)(sh + HDIM);           // [N]   } zeroed
  int* fill     = deg_i + N_NODES;             // [N]   } zeroed
  float* stats  = (float*)(fill + N_NODES);    // [768] } zeroed
  int* rowp     = (int*)(stats + 768);         // [N]
  int* colx     = rowp + N_NODES;              // [E]
  int* start    = colx + N_EDGES;              // [G+1]
  int* part     = start + NGRAPH + 1;          // [256]

  hipMemsetAsync(deg_i, 0, (size_t)(2*N_NODES + 768) * sizeof(int), stream);

  const int TB = 256;
  const int gE  = (N_EDGES + TB - 1)/TB;       // 2344
  const int gN  = (N_NODES + TB - 1)/TB;       // 196
  const int gMM = (N_NODES + 63)/64;           // 782
  const int gAgg= N_NODES / 4;                 // 12500 (1 wave per node)

  const _Float16* Ahf = (const _Float16*)Ah;
  const __half2*  Bh2 = (const __half2*)Bh;

  // ---- weight prep + CSR build ----
  wt_conv<<<192, TB, 0, stream>>>(W1, Wg, W3, Wt1, Wtg, Wt3);
  deg_kernel<<<gE, TB, 0, stream>>>(ei, deg_i);
  dis_kernel<<<gN, TB, 0, stream>>>(deg_i, dis);
  scan_partial<<<SCAN_B, TB, 0, stream>>>(deg_i, part);
  scan_offsets<<<1, TB, 0, stream>>>(part);
  scan_final<<<SCAN_B, TB, 0, stream>>>(deg_i, part, rowp);
  csr_scatter<<<gE, TB, 0, stream>>>(ei, rowp, fill, colx);
  bounds_kernel<<<gN, TB, 0, stream>>>(batch, start);

  // ---- layer 1: GCN ----
  gemm_mfma<false,true,false><<<gMM, TB, 0, stream>>>(x, Wt1, nullptr, nullptr, Ah,
                                                      nullptr, nullptr, nullptr, nullptr);
  gcn_agg<<<gAgg, TB, 0, stream>>>(Ahf, dis, rowp, deg_i, colx, Bh);
  stats_h<<<512, TB, 0, stream>>>(Bh2, stats + 0, stats + 128);
  bnparam<<<1, 128, 0, stream>>>(stats + 0, stats + 128, g1, be1, sc, sh);

  // ---- layer 2: GAT (BN fused into gemm A-frag; att logits fused into epilogue) ----
  gemm_mfma<true,false,true><<<gMM, TB, 0, stream>>>(Bh, Wtg, sc, sh, Ah,
                                                     asr, adt, al_s, al_d);
  gat_agg<<<gAgg, TB, 0, stream>>>(Ahf, al_s, al_d, rowp, deg_i, colx, Bh);
  stats_h<<<512, TB, 0, stream>>>(Bh2, stats + 256, stats + 384);
  bnparam<<<1, 128, 0, stream>>>(stats + 256, stats + 384, g2, be2, sc, sh);

  // ---- layer 3: GCN ----
  gemm_mfma<true,false,false><<<gMM, TB, 0, stream>>>(Bh, Wt3, sc, sh, Ah,
                                                      nullptr, nullptr, nullptr, nullptr);
  gcn_agg<<<gAgg, TB, 0, stream>>>(Ahf, dis, rowp, deg_i, colx, Bh);
  stats_h<<<512, TB, 0, stream>>>(Bh2, stats + 512, stats + 640);
  bnparam<<<1, 128, 0, stream>>>(stats + 512, stats + 640, g3, be3, sc, sh);

  // ---- pool (fused BN+ReLU) + MLP head ----
  pool_h<<<NGRAPH*4, 128, 0, stream>>>(Bh, start, sc, sh, Pq);
  final_kernel<<<NGRAPH, 128, 0, stream>>>(Pq, start, fw1, fb1, fw2, fb2, out);
}

// Round 6
// 457.646 us; speedup vs baseline: 3.3393x; 1.0275x over previous
//
#include <hip/hip_runtime.h>
#include <hip/hip_fp16.h>
#include <cstdint>

#define N_NODES 50000
#define N_EDGES 600000
#define HDIM    128
#define NGRAPH  256
#define EPSBN   1e-5f
#define NEG     0.2f
#define SCAN_B  196   // ceil(50000/256)

__device__ __forceinline__ float lrelu(float v){ return v > 0.f ? v : NEG*v; }

typedef _Float16 f16x8 __attribute__((ext_vector_type(8)));
typedef float    f32x4 __attribute__((ext_vector_type(4)));

// ============ prep: weight transpose/convert + degree count + graph bounds ===
// blocks [0,192): Wt[n][k] = (half)W[k][n] for the 3 weights
// blocks [192, 192+2344): degree atomics
// blocks [192+2344, 192+2344+196): pool segment boundaries
__global__ void prep_kernel(const float* __restrict__ W1, const float* __restrict__ Wg,
                            const float* __restrict__ W3, __half* __restrict__ Wt1,
                            __half* __restrict__ Wtg, __half* __restrict__ Wt3,
                            const int* __restrict__ ei, int* __restrict__ degi,
                            const int* __restrict__ batch, int* __restrict__ start){
  int b = blockIdx.x;
  if (b < 192){
    const float* W = (b < 64) ? W1 : (b < 128 ? Wg : W3);
    __half*     Wt = (b < 64) ? Wt1 : (b < 128 ? Wtg : Wt3);
    int idx = (b & 63)*256 + threadIdx.x;     // 0..16383
    int k = idx >> 7, n = idx & 127;
    Wt[n*128 + k] = __float2half(W[idx]);
  } else if (b < 192 + 2344){
    int e = (b - 192)*256 + threadIdx.x;
    if (e < N_EDGES) atomicAdd(&degi[ei[N_EDGES + e]], 1);
  } else {
    int i = (b - 192 - 2344)*256 + threadIdx.x;
    if (i >= N_NODES) return;
    int bb = batch[i];
    int p = (i == 0) ? -1 : batch[i-1];
    for (int g = p+1; g <= bb; ++g) start[g] = i;
    if (i == N_NODES-1)
      for (int g = bb+1; g <= NGRAPH; ++g) start[g] = N_NODES;
  }
}

// ============ MFMA GEMM (swapped operands): Y = act(X) @ W, fp16 out ============
// mfma(wt_frag, x_frag): lane holds row m = lane&15, cols nt*16 + q*4 + r.
// BN: fused BN+ReLU on X fragment. SCALE: row-scale output by dis[row] (GCN).
// ATT: fused attention logits (GAT).
template<bool BN, bool F32IN, bool ATT, bool SCALE>
__global__ __launch_bounds__(256) void gemm_mfma(const void* __restrict__ Xv,
    const __half* __restrict__ Wt, const float* __restrict__ sc,
    const float* __restrict__ sh, __half* __restrict__ Yh,
    const float* __restrict__ asr, const float* __restrict__ adt,
    float* __restrict__ al_s, float* __restrict__ al_d,
    const float* __restrict__ dis){
  const int t    = threadIdx.x;
  const int wave = t >> 6, lane = t & 63;
  const int q    = lane >> 4, c16 = lane & 15;
  const int m0   = blockIdx.x*64 + wave*16;
  const int row  = m0 + c16;
  const int arow = (row > N_NODES-1) ? N_NODES-1 : row;   // tail clamp (reads only)

  f32x4 acc[8];
#pragma unroll
  for (int i = 0; i < 8; ++i) acc[i] = (f32x4){0.f,0.f,0.f,0.f};

  const f16x8* Wt8 = (const f16x8*)Wt;

#pragma unroll
  for (int kc = 0; kc < 4; ++kc){
    const int kof = kc*32 + q*8;
    f16x8 a;
    if (F32IN){
      const float* xp = (const float*)Xv + (long)arow*128 + kof;
      float4 x0 = *(const float4*)xp;
      float4 x1 = *(const float4*)(xp + 4);
      a[0]=(_Float16)x0.x; a[1]=(_Float16)x0.y; a[2]=(_Float16)x0.z; a[3]=(_Float16)x0.w;
      a[4]=(_Float16)x1.x; a[5]=(_Float16)x1.y; a[6]=(_Float16)x1.z; a[7]=(_Float16)x1.w;
    } else {
      f16x8 raw = *(const f16x8*)((const _Float16*)Xv + (long)arow*128 + kof);
      if (BN){
        float4 s0 = *(const float4*)(sc + kof), s1 = *(const float4*)(sc + kof + 4);
        float4 h0 = *(const float4*)(sh + kof), h1 = *(const float4*)(sh + kof + 4);
        a[0] = (_Float16)fmaxf((float)raw[0]*s0.x + h0.x, 0.f);
        a[1] = (_Float16)fmaxf((float)raw[1]*s0.y + h0.y, 0.f);
        a[2] = (_Float16)fmaxf((float)raw[2]*s0.z + h0.z, 0.f);
        a[3] = (_Float16)fmaxf((float)raw[3]*s0.w + h0.w, 0.f);
        a[4] = (_Float16)fmaxf((float)raw[4]*s1.x + h1.x, 0.f);
        a[5] = (_Float16)fmaxf((float)raw[5]*s1.y + h1.y, 0.f);
        a[6] = (_Float16)fmaxf((float)raw[6]*s1.z + h1.z, 0.f);
        a[7] = (_Float16)fmaxf((float)raw[7]*s1.w + h1.w, 0.f);
      } else {
        a = raw;
      }
    }
#pragma unroll
    for (int nt = 0; nt < 8; ++nt){
      f16x8 b = Wt8[(nt*16 + c16)*16 + kc*4 + q];
      acc[nt] = __builtin_amdgcn_mfma_f32_16x16x32_f16(b, a, acc[nt], 0, 0, 0);
    }
  }
  float rs = SCALE ? dis[arow] : 1.f;
  if (row < N_NODES){
    __half* yp = Yh + (long)row*128 + q*4;
#pragma unroll
    for (int nt = 0; nt < 8; ++nt){
      union { uint2 u; __half2 h[2]; } pk;
      pk.h[0] = __floats2half2_rn(acc[nt][0]*rs, acc[nt][1]*rs);
      pk.h[1] = __floats2half2_rn(acc[nt][2]*rs, acc[nt][3]*rs);
      *(uint2*)(yp + nt*16) = pk.u;
    }
  }
  if (ATT){
    float s = 0.f, d = 0.f;
#pragma unroll
    for (int nt = 0; nt < 8; ++nt){
      float4 av = *(const float4*)(asr + nt*16 + q*4);
      float4 bv = *(const float4*)(adt + nt*16 + q*4);
      s += acc[nt][0]*av.x + acc[nt][1]*av.y + acc[nt][2]*av.z + acc[nt][3]*av.w;
      d += acc[nt][0]*bv.x + acc[nt][1]*bv.y + acc[nt][2]*bv.z + acc[nt][3]*bv.w;
    }
    s += __shfl_xor(s, 16); s += __shfl_xor(s, 32);
    d += __shfl_xor(d, 16); d += __shfl_xor(d, 32);
    if (q == 0 && row < N_NODES){ al_s[row] = s; al_d[row] = d; }
  }
}

// ============ CSR build ============
__global__ void scan_partial(const int* __restrict__ degi, int* __restrict__ part,
                             float* __restrict__ dis){
  __shared__ int sm[256];
  int t = threadIdx.x; int i = blockIdx.x*256 + t;
  int v = (i < N_NODES) ? degi[i] : 0;
  if (i < N_NODES) dis[i] = rsqrtf((float)v + 1.f);   // +1 = self loop
  sm[t] = v;
  __syncthreads();
  for (int off = 128; off; off >>= 1){
    if (t < off) sm[t] += sm[t + off];
    __syncthreads();
  }
  if (t == 0) part[blockIdx.x] = sm[0];
}
__global__ void scan_offsets(int* part){
  __shared__ int sm[256];
  int t = threadIdx.x;
  int v = (t < SCAN_B) ? part[t] : 0;
  sm[t] = v; __syncthreads();
  for (int off = 1; off < 256; off <<= 1){
    int add = (t >= off) ? sm[t - off] : 0;
    __syncthreads();
    sm[t] += add; __syncthreads();
  }
  if (t < SCAN_B) part[t] = sm[t] - v;
}
__global__ void scan_final(const int* __restrict__ degi, const int* __restrict__ part,
                           int* __restrict__ rowp){
  __shared__ int sm[256];
  int t = threadIdx.x; int i = blockIdx.x*256 + t;
  int v = (i < N_NODES) ? degi[i] : 0;
  sm[t] = v; __syncthreads();
  for (int off = 1; off < 256; off <<= 1){
    int add = (t >= off) ? sm[t - off] : 0;
    __syncthreads();
    sm[t] += add; __syncthreads();
  }
  if (i < N_NODES) rowp[i] = part[blockIdx.x] + sm[t] - v;
}
__global__ void csr_scatter(const int* __restrict__ ei, const int* __restrict__ rowp,
                            int* __restrict__ fill, int* __restrict__ colx){
  int e = blockIdx.x*256 + threadIdx.x;
  if (e >= N_EDGES) return;
  int s = ei[e], d = ei[N_EDGES + e];
  int pos = rowp[d] + atomicAdd(&fill[d], 1);
  colx[pos] = s;
}

// ============ GCN aggregation: rows are pre-scaled by dis -> plain row sum ===
// B[n] = dis[n] * ( sum_{s in nbr(n)} Ah'[s] + Ah'[n] ),  Ah' = dis*(X@W)
__global__ __launch_bounds__(256) void gcn_agg(const _Float16* __restrict__ Ah,
    const float* __restrict__ dis, const int* __restrict__ rowp,
    const int* __restrict__ degi, const int* __restrict__ colx,
    __half* __restrict__ Bh){
  const int n = blockIdx.x*4 + (threadIdx.x >> 6);
  const int lane = threadIdx.x & 63;
  const int g = lane >> 4, p = lane & 15;
  float acc[8] = {0,0,0,0,0,0,0,0};
  if (g == 0){
    f16x8 self = *(const f16x8*)(Ah + (long)n*128 + p*8);
#pragma unroll
    for (int i = 0; i < 8; ++i) acc[i] = (float)self[i];
  }
  const int e0 = rowp[n], cnt = degi[n];
  for (int base = 0; base < cnt; base += 64){
    int idx = base + lane;
    int s = (idx < cnt) ? colx[e0 + idx] : 0;
    int nit = min(64, cnt - base);
    int full = nit & ~3;
    for (int j = 0; j < full; j += 4){
      int sj = __shfl(s, j + g);
      f16x8 r = *(const f16x8*)(Ah + (long)sj*128 + p*8);
#pragma unroll
      for (int i = 0; i < 8; ++i) acc[i] += (float)r[i];
    }
    if (full < nit){                       // remainder 1..3 edges, group-uniform guard
      int sj = __shfl(s, full + g);
      if (g < nit - full){
        f16x8 r = *(const f16x8*)(Ah + (long)sj*128 + p*8);
#pragma unroll
        for (int i = 0; i < 8; ++i) acc[i] += (float)r[i];
      }
    }
  }
#pragma unroll
  for (int i = 0; i < 8; ++i){
    acc[i] += __shfl_xor(acc[i], 16);
    acc[i] += __shfl_xor(acc[i], 32);
  }
  if (g == 0){
    float dn = dis[n];
    union { uint4 u; __half2 h[4]; } pk;
#pragma unroll
    for (int i = 0; i < 4; ++i)
      pk.h[i] = __floats2half2_rn(acc[2*i]*dn, acc[2*i+1]*dn);
    *(uint4*)(Bh + (long)n*128 + p*8) = pk.u;
  }
}

// ============ GAT aggregation: single colx pass (reg-cached), 1 exp/edge ======
__global__ __launch_bounds__(256) void gat_agg(const _Float16* __restrict__ Ah,
    const float* __restrict__ al_s, const float* __restrict__ al_d,
    const int* __restrict__ rowp, const int* __restrict__ degi,
    const int* __restrict__ colx, __half* __restrict__ Bh){
  const int n = blockIdx.x*4 + (threadIdx.x >> 6);
  const int lane = threadIdx.x & 63;
  const int g = lane >> 4, p = lane & 15;
  const float adn = al_d[n];
  const float lself = lrelu(al_s[n] + adn);
  const int e0 = rowp[n], cnt = degi[n];
  // load first (<=64) edges once, cache in registers
  int sReg = 0; float lv = -1e30f;
  if (lane < cnt){ sReg = colx[e0 + lane]; lv = lrelu(al_s[sReg] + adn); }
  float m = fmaxf(lself, lv);
  for (int base = 64; base < cnt; base += 64){     // rare: degree > 64
    int idx = base + lane;
    if (idx < cnt) m = fmaxf(m, lrelu(al_s[colx[e0 + idx]] + adn));
  }
#pragma unroll
  for (int off = 32; off; off >>= 1) m = fmaxf(m, __shfl_xor(m, off));
  const float exs = __expf(lself - m);
  float w = __expf(lv - m);                        // inactive lanes: underflows to 0
  float dpart = w;
  float acc[8] = {0,0,0,0,0,0,0,0};
  if (g == 0){
    f16x8 self = *(const f16x8*)(Ah + (long)n*128 + p*8);
#pragma unroll
    for (int i = 0; i < 8; ++i) acc[i] = exs * (float)self[i];
  }
  {
    int nit = min(64, cnt);
    for (int j = 0; j < nit; j += 4){
      int   sj = __shfl(sReg, j + g);              // w=0 masks inactive sources
      float wj = __shfl(w,    j + g);
      f16x8 r = *(const f16x8*)(Ah + (long)sj*128 + p*8);
#pragma unroll
      for (int i = 0; i < 8; ++i) acc[i] += wj * (float)r[i];
    }
  }
  for (int base = 64; base < cnt; base += 64){     // rare: degree > 64
    int idx = base + lane;
    int s2 = 0; float w2 = 0.f;
    if (idx < cnt){ s2 = colx[e0 + idx]; w2 = __expf(lrelu(al_s[s2] + adn) - m); }
    dpart += w2;
    int nit = min(64, cnt - base);
    for (int j = 0; j < nit; j += 4){
      int   sj = __shfl(s2, j + g);
      float wj = __shfl(w2, j + g);
      f16x8 r = *(const f16x8*)(Ah + (long)sj*128 + p*8);
#pragma unroll
      for (int i = 0; i < 8; ++i) acc[i] += wj * (float)r[i];
    }
  }
#pragma unroll
  for (int off = 32; off; off >>= 1) dpart += __shfl_xor(dpart, off);
#pragma unroll
  for (int i = 0; i < 8; ++i){
    acc[i] += __shfl_xor(acc[i], 16);
    acc[i] += __shfl_xor(acc[i], 32);
  }
  if (g == 0){
    float rinv = 1.f / (dpart + exs);
    union { uint4 u; __half2 h[4]; } pk;
#pragma unroll
    for (int i = 0; i < 4; ++i)
      pk.h[i] = __floats2half2_rn(acc[2*i]*rinv, acc[2*i+1]*rinv);
    *(uint4*)(Bh + (long)n*128 + p*8) = pk.u;
  }
}

// ============ BN stats over fp16 tensor ============
__global__ void stats_h(const __half2* __restrict__ X2,
                        float* __restrict__ S, float* __restrict__ Q){
  __shared__ float s0m[256], s1m[256], q0m[256], q1m[256];
  int t = threadIdx.x;
  float s0=0,s1=0,q0=0,q1=0;
  int stride = gridDim.x*256;
  const int total = N_NODES*64;
  for (int idx = blockIdx.x*256 + t; idx < total; idx += stride){
    float2 f = __half22float2(X2[idx]);
    s0 += f.x; q0 += f.x*f.x; s1 += f.y; q1 += f.y*f.y;
  }
  s0m[t]=s0; s1m[t]=s1; q0m[t]=q0; q1m[t]=q1;
  __syncthreads();
  if (t < 64){
    float a0 = s0m[t]+s0m[t+64]+s0m[t+128]+s0m[t+192];
    float a1 = s1m[t]+s1m[t+64]+s1m[t+128]+s1m[t+192];
    float b0 = q0m[t]+q0m[t+64]+q0m[t+128]+q0m[t+192];
    float b1 = q1m[t]+q1m[t+64]+q1m[t+128]+q1m[t+192];
    atomicAdd(&S[2*t],   a0); atomicAdd(&S[2*t+1], a1);
    atomicAdd(&Q[2*t],   b0); atomicAdd(&Q[2*t+1], b1);
  }
}
__global__ void bnparam(const float* __restrict__ S, const float* __restrict__ Q,
                        const float* __restrict__ g, const float* __restrict__ be,
                        float* __restrict__ sc, float* __restrict__ sh){
  int c = threadIdx.x;
  float mean = S[c] / (float)N_NODES;
  float var  = fmaxf(Q[c]/(float)N_NODES - mean*mean, 0.f);
  float scale = g[c]*rsqrtf(var + EPSBN);
  sc[c] = scale;
  sh[c] = be[c] - mean*scale;
}

// ============ pooling (fused BN+ReLU), 4 blocks per graph ============
__global__ void pool_h(const __half* __restrict__ Bh, const int* __restrict__ start,
                       const float* __restrict__ sc, const float* __restrict__ sh,
                       float* __restrict__ Pq){
  int g = blockIdx.x >> 2, q = blockIdx.x & 3, f = threadIdx.x;
  int s0 = start[g], len = start[g+1] - s0;
  int n0 = s0 + (len*q)/4, n1 = s0 + (len*(q+1))/4;
  float scl = sc[f], shf = sh[f];
  float acc = 0.f;
  for (int n = n0; n < n1; ++n)
    acc += fmaxf(__half2float(Bh[(long)n*128 + f])*scl + shf, 0.f);
  Pq[(long)blockIdx.x*128 + f] = acc;
}

// ============ MLP head ============
__global__ void final_kernel(const float* __restrict__ Pq, const int* __restrict__ start,
                             const float* __restrict__ fw1, const float* __restrict__ fb1,
                             const float* __restrict__ fw2, const float* __restrict__ fb2,
                             float* __restrict__ out){
  __shared__ float p[128];
  __shared__ float red[2];
  int g = blockIdx.x, t = threadIdx.x;
  float cnt = fmaxf((float)(start[g+1] - start[g]), 1.f);
  float sum = Pq[(long)(g*4+0)*128+t] + Pq[(long)(g*4+1)*128+t]
            + Pq[(long)(g*4+2)*128+t] + Pq[(long)(g*4+3)*128+t];
  p[t] = sum / cnt;
  __syncthreads();
  float acc = fb1[t];
  for (int k = 0; k < 128; ++k) acc += p[k]*fw1[k*128 + t];
  float z = fmaxf(acc, 0.f) * fw2[t];
  for (int off = 32; off; off >>= 1) z += __shfl_down(z, off);
  if ((t & 63) == 0) red[t >> 6] = z;
  __syncthreads();
  if (t == 0) out[g] = red[0] + red[1] + fb2[0];
}

extern "C" void kernel_launch(void* const* d_in, const int* in_sizes, int n_in,
                              void* d_out, int out_size, void* d_ws, size_t ws_size,
                              hipStream_t stream){
  const float* x    = (const float*)d_in[0];
  const int*   ei   = (const int*)d_in[1];
  const int*   batch= (const int*)d_in[2];
  const float* W1   = (const float*)d_in[3];
  const float* g1   = (const float*)d_in[5];
  const float* be1  = (const float*)d_in[6];
  const float* Wg   = (const float*)d_in[7];
  const float* asr  = (const float*)d_in[8];
  const float* adt  = (const float*)d_in[9];
  const float* g2   = (const float*)d_in[11];
  const float* be2  = (const float*)d_in[12];
  const float* W3   = (const float*)d_in[13];
  const float* g3   = (const float*)d_in[15];
  const float* be3  = (const float*)d_in[16];
  const float* fw1  = (const float*)d_in[17];
  const float* fb1  = (const float*)d_in[18];
  const float* fw2  = (const float*)d_in[19];
  const float* fb2  = (const float*)d_in[20];
  float* out = (float*)d_out;

  const long NH = (long)N_NODES*HDIM;          // 6.4M
  __half* Ah    = (__half*)d_ws;               // [N,H] fp16 (gemm out)
  __half* Bh    = Ah + NH;                     // [N,H] fp16 (agg out)
  __half* Wt1   = Bh + NH;                     // [128,128] fp16 transposed
  __half* Wtg   = Wt1 + 16384;
  __half* Wt3   = Wtg + 16384;
  float* dis    = (float*)(Wt3 + 16384);       // [N]
  float* al_s   = dis + N_NODES;               // [N]
  float* al_d   = al_s + N_NODES;              // [N]
  float* Pq     = al_d + N_NODES;              // [G*4,H]
  float* sc     = Pq + (long)NGRAPH*4*HDIM;    // [128]
  float* sh     = sc + HDIM;                   // [128]
  int* deg_i    = (int*)(sh + HDIM);           // [N]   } zeroed
  int* fill     = deg_i + N_NODES;             // [N]   } zeroed
  float* stats  = (float*)(fill + N_NODES);    // [768] } zeroed
  int* rowp     = (int*)(stats + 768);         // [N]
  int* colx     = rowp + N_NODES;              // [E]
  int* start    = colx + N_EDGES;              // [G+1]
  int* part     = start + NGRAPH + 1;          // [256]

  hipMemsetAsync(deg_i, 0, (size_t)(2*N_NODES + 768) * sizeof(int), stream);

  const int TB = 256;
  const int gE  = (N_EDGES + TB - 1)/TB;       // 2344
  const int gMM = (N_NODES + 63)/64;           // 782
  const int gAgg= N_NODES / 4;                 // 12500 (1 wave per node)

  const _Float16* Ahf = (const _Float16*)Ah;
  const __half2*  Bh2 = (const __half2*)Bh;

  // ---- prep (weights + degree + bounds) + CSR build ----
  prep_kernel<<<192 + gE + SCAN_B, TB, 0, stream>>>(W1, Wg, W3, Wt1, Wtg, Wt3,
                                                    ei, deg_i, batch, start);
  scan_partial<<<SCAN_B, TB, 0, stream>>>(deg_i, part, dis);
  scan_offsets<<<1, TB, 0, stream>>>(part);
  scan_final<<<SCAN_B, TB, 0, stream>>>(deg_i, part, rowp);
  csr_scatter<<<gE, TB, 0, stream>>>(ei, rowp, fill, colx);

  // ---- layer 1: GCN (dis row-scale fused into gemm epilogue) ----
  gemm_mfma<false,true,false,true><<<gMM, TB, 0, stream>>>(x, Wt1, nullptr, nullptr, Ah,
                                                 nullptr, nullptr, nullptr, nullptr, dis);
  gcn_agg<<<gAgg, TB, 0, stream>>>(Ahf, dis, rowp, deg_i, colx, Bh);
  stats_h<<<512, TB, 0, stream>>>(Bh2, stats + 0, stats + 128);
  bnparam<<<1, 128, 0, stream>>>(stats + 0, stats + 128, g1, be1, sc, sh);

  // ---- layer 2: GAT (BN fused into gemm A-frag; att logits fused into epilogue) ----
  gemm_mfma<true,false,true,false><<<gMM, TB, 0, stream>>>(Bh, Wtg, sc, sh, Ah,
                                                 asr, adt, al_s, al_d, nullptr);
  gat_agg<<<gAgg, TB, 0, stream>>>(Ahf, al_s, al_d, rowp, deg_i, colx, Bh);
  stats_h<<<512, TB, 0, stream>>>(Bh2, stats + 256, stats + 384);
  bnparam<<<1, 128, 0, stream>>>(stats + 256, stats + 384, g2, be2, sc, sh);

  // ---- layer 3: GCN ----
  gemm_mfma<true,false,false,true><<<gMM, TB, 0, stream>>>(Bh, Wt3, sc, sh, Ah,
                                                 nullptr, nullptr, nullptr, nullptr, dis);
  gcn_agg<<<gAgg, TB, 0, stream>>>(Ahf, dis, rowp, deg_i, colx, Bh);
  stats_h<<<512, TB, 0, stream>>>(Bh2, stats + 512, stats + 640);
  bnparam<<<1, 128, 0, stream>>>(stats + 512, stats + 640, g3, be3, sc, sh);

  // ---- pool (fused BN+ReLU) + MLP head ----
  pool_h<<<NGRAPH*4, 128, 0, stream>>>(Bh, start, sc, sh, Pq);
  final_kernel<<<NGRAPH, 128, 0, stream>>>(Pq, start, fw1, fb1, fw2, fb2, out);
}

// Round 7
// 455.097 us; speedup vs baseline: 3.3581x; 1.0056x over previous
//
#include <hip/hip_runtime.h>
#include <hip/hip_fp16.h>
#include <cstdint>

#define N_NODES 50000
#define N_EDGES 600000
#define HDIM    128
#define NGRAPH  256
#define EPSBN   1e-5f
#define NEG     0.2f
#define SCAN_B  196   // ceil(50000/256)

__device__ __forceinline__ float lrelu(float v){ return v > 0.f ? v : NEG*v; }

typedef _Float16 f16x8 __attribute__((ext_vector_type(8)));
typedef float    f32x4 __attribute__((ext_vector_type(4)));

// ============ prep: weight transpose/convert + degree count + graph bounds ===
__global__ void prep_kernel(const float* __restrict__ W1, const float* __restrict__ Wg,
                            const float* __restrict__ W3, __half* __restrict__ Wt1,
                            __half* __restrict__ Wtg, __half* __restrict__ Wt3,
                            const int* __restrict__ ei, int* __restrict__ degi,
                            const int* __restrict__ batch, int* __restrict__ start){
  int b = blockIdx.x;
  if (b < 192){
    const float* W = (b < 64) ? W1 : (b < 128 ? Wg : W3);
    __half*     Wt = (b < 64) ? Wt1 : (b < 128 ? Wtg : Wt3);
    int idx = (b & 63)*256 + threadIdx.x;     // 0..16383
    int k = idx >> 7, n = idx & 127;
    Wt[n*128 + k] = __float2half(W[idx]);
  } else if (b < 192 + 2344){
    int e = (b - 192)*256 + threadIdx.x;
    if (e < N_EDGES) atomicAdd(&degi[ei[N_EDGES + e]], 1);
  } else {
    int i = (b - 192 - 2344)*256 + threadIdx.x;
    if (i >= N_NODES) return;
    int bb = batch[i];
    int p = (i == 0) ? -1 : batch[i-1];
    for (int g = p+1; g <= bb; ++g) start[g] = i;
    if (i == N_NODES-1)
      for (int g = bb+1; g <= NGRAPH; ++g) start[g] = N_NODES;
  }
}

// ============ MFMA GEMM (swapped operands): Y = act(X) @ W, fp16 out ============
// BN: fused packed-fp16 BN+ReLU on X fragment. SCALE: row-scale out by dis (GCN).
// ATT: fused attention logits (GAT).
template<bool BN, bool F32IN, bool ATT, bool SCALE>
__global__ __launch_bounds__(256) void gemm_mfma(const void* __restrict__ Xv,
    const __half* __restrict__ Wt, const __half* __restrict__ scH,
    const __half* __restrict__ shH, __half* __restrict__ Yh,
    const float* __restrict__ asr, const float* __restrict__ adt,
    float* __restrict__ al_s, float* __restrict__ al_d,
    const float* __restrict__ dis){
  const int t    = threadIdx.x;
  const int wave = t >> 6, lane = t & 63;
  const int q    = lane >> 4, c16 = lane & 15;
  const int m0   = blockIdx.x*64 + wave*16;
  const int row  = m0 + c16;
  const int arow = (row > N_NODES-1) ? N_NODES-1 : row;   // tail clamp (reads only)

  f32x4 acc[8];
#pragma unroll
  for (int i = 0; i < 8; ++i) acc[i] = (f32x4){0.f,0.f,0.f,0.f};

  const f16x8* Wt8 = (const f16x8*)Wt;

#pragma unroll
  for (int kc = 0; kc < 4; ++kc){
    const int kof = kc*32 + q*8;
    f16x8 a;
    if (F32IN){
      const float* xp = (const float*)Xv + (long)arow*128 + kof;
      float4 x0 = *(const float4*)xp;
      float4 x1 = *(const float4*)(xp + 4);
      a[0]=(_Float16)x0.x; a[1]=(_Float16)x0.y; a[2]=(_Float16)x0.z; a[3]=(_Float16)x0.w;
      a[4]=(_Float16)x1.x; a[5]=(_Float16)x1.y; a[6]=(_Float16)x1.z; a[7]=(_Float16)x1.w;
    } else {
      f16x8 raw = *(const f16x8*)((const _Float16*)Xv + (long)arow*128 + kof);
      if (BN){
        f16x8 scv = *(const f16x8*)((const _Float16*)scH + kof);
        f16x8 shv = *(const f16x8*)((const _Float16*)shH + kof);
#pragma unroll
        for (int i = 0; i < 8; ++i){
          _Float16 v = (_Float16)(raw[i]*scv[i] + shv[i]);
          a[i] = v > (_Float16)0 ? v : (_Float16)0;
        }
      } else {
        a = raw;
      }
    }
#pragma unroll
    for (int nt = 0; nt < 8; ++nt){
      f16x8 b = Wt8[(nt*16 + c16)*16 + kc*4 + q];
      acc[nt] = __builtin_amdgcn_mfma_f32_16x16x32_f16(b, a, acc[nt], 0, 0, 0);
    }
  }
  float rs = SCALE ? dis[arow] : 1.f;
  if (row < N_NODES){
    __half* yp = Yh + (long)row*128 + q*4;
#pragma unroll
    for (int nt = 0; nt < 8; ++nt){
      union { uint2 u; __half2 h[2]; } pk;
      pk.h[0] = __floats2half2_rn(acc[nt][0]*rs, acc[nt][1]*rs);
      pk.h[1] = __floats2half2_rn(acc[nt][2]*rs, acc[nt][3]*rs);
      *(uint2*)(yp + nt*16) = pk.u;
    }
  }
  if (ATT){
    float s = 0.f, d = 0.f;
#pragma unroll
    for (int nt = 0; nt < 8; ++nt){
      float4 av = *(const float4*)(asr + nt*16 + q*4);
      float4 bv = *(const float4*)(adt + nt*16 + q*4);
      s += acc[nt][0]*av.x + acc[nt][1]*av.y + acc[nt][2]*av.z + acc[nt][3]*av.w;
      d += acc[nt][0]*bv.x + acc[nt][1]*bv.y + acc[nt][2]*bv.z + acc[nt][3]*bv.w;
    }
    s += __shfl_xor(s, 16); s += __shfl_xor(s, 32);
    d += __shfl_xor(d, 16); d += __shfl_xor(d, 32);
    if (q == 0 && row < N_NODES){ al_s[row] = s; al_d[row] = d; }
  }
}

// ============ CSR build ============
__global__ void scan_partial(const int* __restrict__ degi, int* __restrict__ part,
                             float* __restrict__ dis){
  __shared__ int sm[256];
  int t = threadIdx.x; int i = blockIdx.x*256 + t;
  int v = (i < N_NODES) ? degi[i] : 0;
  if (i < N_NODES) dis[i] = rsqrtf((float)v + 1.f);   // +1 = self loop
  sm[t] = v;
  __syncthreads();
  for (int off = 128; off; off >>= 1){
    if (t < off) sm[t] += sm[t + off];
    __syncthreads();
  }
  if (t == 0) part[blockIdx.x] = sm[0];
}
__global__ void scan_offsets(int* part){
  __shared__ int sm[256];
  int t = threadIdx.x;
  int v = (t < SCAN_B) ? part[t] : 0;
  sm[t] = v; __syncthreads();
  for (int off = 1; off < 256; off <<= 1){
    int add = (t >= off) ? sm[t - off] : 0;
    __syncthreads();
    sm[t] += add; __syncthreads();
  }
  if (t < SCAN_B) part[t] = sm[t] - v;
}
__global__ void scan_final(const int* __restrict__ degi, const int* __restrict__ part,
                           int* __restrict__ rowp){
  __shared__ int sm[256];
  int t = threadIdx.x; int i = blockIdx.x*256 + t;
  int v = (i < N_NODES) ? degi[i] : 0;
  sm[t] = v; __syncthreads();
  for (int off = 1; off < 256; off <<= 1){
    int add = (t >= off) ? sm[t - off] : 0;
    __syncthreads();
    sm[t] += add; __syncthreads();
  }
  if (i < N_NODES) rowp[i] = part[blockIdx.x] + sm[t] - v;
}
__global__ void csr_scatter(const int* __restrict__ ei, const int* __restrict__ rowp,
                            int* __restrict__ fill, int* __restrict__ colx){
  int e = blockIdx.x*256 + threadIdx.x;
  if (e >= N_EDGES) return;
  int s = ei[e], d = ei[N_EDGES + e];
  int pos = rowp[d] + atomicAdd(&fill[d], 1);
  colx[pos] = s;
}

// ============ GCN aggregation: weighted row-sum (w in {0,1}), 2 loads in flight
// B[n] = dis[n] * ( sum_{s in nbr(n)} Ah'[s] + Ah'[n] ),  Ah' = dis*(X@W)
__global__ __launch_bounds__(256) void gcn_agg(const _Float16* __restrict__ Ah,
    const float* __restrict__ dis, const int* __restrict__ rowp,
    const int* __restrict__ degi, const int* __restrict__ colx,
    __half* __restrict__ Bh){
  const int n = blockIdx.x*4 + (threadIdx.x >> 6);
  const int lane = threadIdx.x & 63;
  const int g = lane >> 4, p = lane & 15;
  float acc[8] = {0,0,0,0,0,0,0,0};
  if (g == 0){
    f16x8 self = *(const f16x8*)(Ah + (long)n*128 + p*8);
#pragma unroll
    for (int i = 0; i < 8; ++i) acc[i] = (float)self[i];
  }
  const int e0 = rowp[n], cnt = degi[n];
  for (int base = 0; base < cnt; base += 64){
    int idx = base + lane;
    int s = 0; float w = 0.f;
    if (idx < cnt){ s = colx[e0 + idx]; w = 1.f; }
    int nit = min(64, cnt - base);
    int j = 0;
    for (; j + 8 <= nit; j += 8){
      int   s0 = __shfl(s, j + g),      s1 = __shfl(s, j + 4 + g);
      float w0 = __shfl(w, j + g),      w1 = __shfl(w, j + 4 + g);
      f16x8 r0 = *(const f16x8*)(Ah + (long)s0*128 + p*8);
      f16x8 r1 = *(const f16x8*)(Ah + (long)s1*128 + p*8);
#pragma unroll
      for (int i = 0; i < 8; ++i) acc[i] += w0 * (float)r0[i];
#pragma unroll
      for (int i = 0; i < 8; ++i) acc[i] += w1 * (float)r1[i];
    }
    for (; j < nit; j += 4){               // w=0 masks lanes past cnt
      int   sj = __shfl(s, j + g);
      float wj = __shfl(w, j + g);
      f16x8 r = *(const f16x8*)(Ah + (long)sj*128 + p*8);
#pragma unroll
      for (int i = 0; i < 8; ++i) acc[i] += wj * (float)r[i];
    }
  }
#pragma unroll
  for (int i = 0; i < 8; ++i){
    acc[i] += __shfl_xor(acc[i], 16);
    acc[i] += __shfl_xor(acc[i], 32);
  }
  if (g == 0){
    float dn = dis[n];
    union { uint4 u; __half2 h[4]; } pk;
#pragma unroll
    for (int i = 0; i < 4; ++i)
      pk.h[i] = __floats2half2_rn(acc[2*i]*dn, acc[2*i+1]*dn);
    *(uint4*)(Bh + (long)n*128 + p*8) = pk.u;
  }
}

// ============ GAT aggregation: single colx pass, 2 loads in flight ============
__global__ __launch_bounds__(256) void gat_agg(const _Float16* __restrict__ Ah,
    const float* __restrict__ al_s, const float* __restrict__ al_d,
    const int* __restrict__ rowp, const int* __restrict__ degi,
    const int* __restrict__ colx, __half* __restrict__ Bh){
  const int n = blockIdx.x*4 + (threadIdx.x >> 6);
  const int lane = threadIdx.x & 63;
  const int g = lane >> 4, p = lane & 15;
  const float adn = al_d[n];
  const float lself = lrelu(al_s[n] + adn);
  const int e0 = rowp[n], cnt = degi[n];
  // load first (<=64) edges once, cache in registers
  int sReg = 0; float lv = -1e30f;
  if (lane < cnt){ sReg = colx[e0 + lane]; lv = lrelu(al_s[sReg] + adn); }
  float m = fmaxf(lself, lv);
  for (int base = 64; base < cnt; base += 64){     // rare: degree > 64
    int idx = base + lane;
    if (idx < cnt) m = fmaxf(m, lrelu(al_s[colx[e0 + idx]] + adn));
  }
#pragma unroll
  for (int off = 32; off; off >>= 1) m = fmaxf(m, __shfl_xor(m, off));
  const float exs = __expf(lself - m);
  float w = __expf(lv - m);                        // inactive lanes -> 0
  float dpart = w;
  float acc[8] = {0,0,0,0,0,0,0,0};
  if (g == 0){
    f16x8 self = *(const f16x8*)(Ah + (long)n*128 + p*8);
#pragma unroll
    for (int i = 0; i < 8; ++i) acc[i] = exs * (float)self[i];
  }
  {
    int nit = min(64, cnt);
    int j = 0;
    for (; j + 8 <= nit; j += 8){
      int   s0 = __shfl(sReg, j + g),   s1 = __shfl(sReg, j + 4 + g);
      float w0 = __shfl(w,    j + g),   w1 = __shfl(w,    j + 4 + g);
      f16x8 r0 = *(const f16x8*)(Ah + (long)s0*128 + p*8);
      f16x8 r1 = *(const f16x8*)(Ah + (long)s1*128 + p*8);
#pragma unroll
      for (int i = 0; i < 8; ++i) acc[i] += w0 * (float)r0[i];
#pragma unroll
      for (int i = 0; i < 8; ++i) acc[i] += w1 * (float)r1[i];
    }
    for (; j < nit; j += 4){                       // w=0 masks
      int   sj = __shfl(sReg, j + g);
      float wj = __shfl(w,    j + g);
      f16x8 r = *(const f16x8*)(Ah + (long)sj*128 + p*8);
#pragma unroll
      for (int i = 0; i < 8; ++i) acc[i] += wj * (float)r[i];
    }
  }
  for (int base = 64; base < cnt; base += 64){     // rare: degree > 64
    int idx = base + lane;
    int s2 = 0; float w2 = 0.f;
    if (idx < cnt){ s2 = colx[e0 + idx]; w2 = __expf(lrelu(al_s[s2] + adn) - m); }
    dpart += w2;
    int nit = min(64, cnt - base);
    for (int j = 0; j < nit; j += 4){
      int   sj = __shfl(s2, j + g);
      float wj = __shfl(w2, j + g);
      f16x8 r = *(const f16x8*)(Ah + (long)sj*128 + p*8);
#pragma unroll
      for (int i = 0; i < 8; ++i) acc[i] += wj * (float)r[i];
    }
  }
#pragma unroll
  for (int off = 32; off; off >>= 1) dpart += __shfl_xor(dpart, off);
#pragma unroll
  for (int i = 0; i < 8; ++i){
    acc[i] += __shfl_xor(acc[i], 16);
    acc[i] += __shfl_xor(acc[i], 32);
  }
  if (g == 0){
    float rinv = 1.f / (dpart + exs);
    union { uint4 u; __half2 h[4]; } pk;
#pragma unroll
    for (int i = 0; i < 4; ++i)
      pk.h[i] = __floats2half2_rn(acc[2*i]*rinv, acc[2*i+1]*rinv);
    *(uint4*)(Bh + (long)n*128 + p*8) = pk.u;
  }
}

// ============ BN stats over fp16 tensor ============
__global__ void stats_h(const __half2* __restrict__ X2,
                        float* __restrict__ S, float* __restrict__ Q){
  __shared__ float s0m[256], s1m[256], q0m[256], q1m[256];
  int t = threadIdx.x;
  float s0=0,s1=0,q0=0,q1=0;
  int stride = gridDim.x*256;
  const int total = N_NODES*64;
  for (int idx = blockIdx.x*256 + t; idx < total; idx += stride){
    float2 f = __half22float2(X2[idx]);
    s0 += f.x; q0 += f.x*f.x; s1 += f.y; q1 += f.y*f.y;
  }
  s0m[t]=s0; s1m[t]=s1; q0m[t]=q0; q1m[t]=q1;
  __syncthreads();
  if (t < 64){
    float a0 = s0m[t]+s0m[t+64]+s0m[t+128]+s0m[t+192];
    float a1 = s1m[t]+s1m[t+64]+s1m[t+128]+s1m[t+192];
    float b0 = q0m[t]+q0m[t+64]+q0m[t+128]+q0m[t+192];
    float b1 = q1m[t]+q1m[t+64]+q1m[t+128]+q1m[t+192];
    atomicAdd(&S[2*t],   a0); atomicAdd(&S[2*t+1], a1);
    atomicAdd(&Q[2*t],   b0); atomicAdd(&Q[2*t+1], b1);
  }
}
// fp32 params (pool) + packed fp16 params (gemm A-frag)
__global__ void bnparam(const float* __restrict__ S, const float* __restrict__ Q,
                        const float* __restrict__ g, const float* __restrict__ be,
                        float* __restrict__ sc, float* __restrict__ sh,
                        __half* __restrict__ scH, __half* __restrict__ shH){
  int c = threadIdx.x;
  float mean = S[c] / (float)N_NODES;
  float var  = fmaxf(Q[c]/(float)N_NODES - mean*mean, 0.f);
  float scale = g[c]*rsqrtf(var + EPSBN);
  float shift = be[c] - mean*scale;
  sc[c] = scale;  sh[c] = shift;
  scH[c] = __float2half(scale);
  shH[c] = __float2half(shift);
}

// ============ pooling (fused BN+ReLU), 4 blocks per graph ============
__global__ void pool_h(const __half* __restrict__ Bh, const int* __restrict__ start,
                       const float* __restrict__ sc, const float* __restrict__ sh,
                       float* __restrict__ Pq){
  int g = blockIdx.x >> 2, q = blockIdx.x & 3, f = threadIdx.x;
  int s0 = start[g], len = start[g+1] - s0;
  int n0 = s0 + (len*q)/4, n1 = s0 + (len*(q+1))/4;
  float scl = sc[f], shf = sh[f];
  float acc = 0.f;
  for (int n = n0; n < n1; ++n)
    acc += fmaxf(__half2float(Bh[(long)n*128 + f])*scl + shf, 0.f);
  Pq[(long)blockIdx.x*128 + f] = acc;
}

// ============ MLP head ============
__global__ void final_kernel(const float* __restrict__ Pq, const int* __restrict__ start,
                             const float* __restrict__ fw1, const float* __restrict__ fb1,
                             const float* __restrict__ fw2, const float* __restrict__ fb2,
                             float* __restrict__ out){
  __shared__ float p[128];
  __shared__ float red[2];
  int g = blockIdx.x, t = threadIdx.x;
  float cnt = fmaxf((float)(start[g+1] - start[g]), 1.f);
  float sum = Pq[(long)(g*4+0)*128+t] + Pq[(long)(g*4+1)*128+t]
            + Pq[(long)(g*4+2)*128+t] + Pq[(long)(g*4+3)*128+t];
  p[t] = sum / cnt;
  __syncthreads();
  float acc = fb1[t];
  for (int k = 0; k < 128; ++k) acc += p[k]*fw1[k*128 + t];
  float z = fmaxf(acc, 0.f) * fw2[t];
  for (int off = 32; off; off >>= 1) z += __shfl_down(z, off);
  if ((t & 63) == 0) red[t >> 6] = z;
  __syncthreads();
  if (t == 0) out[g] = red[0] + red[1] + fb2[0];
}

extern "C" void kernel_launch(void* const* d_in, const int* in_sizes, int n_in,
                              void* d_out, int out_size, void* d_ws, size_t ws_size,
                              hipStream_t stream){
  const float* x    = (const float*)d_in[0];
  const int*   ei   = (const int*)d_in[1];
  const int*   batch= (const int*)d_in[2];
  const float* W1   = (const float*)d_in[3];
  const float* g1   = (const float*)d_in[5];
  const float* be1  = (const float*)d_in[6];
  const float* Wg   = (const float*)d_in[7];
  const float* asr  = (const float*)d_in[8];
  const float* adt  = (const float*)d_in[9];
  const float* g2   = (const float*)d_in[11];
  const float* be2  = (const float*)d_in[12];
  const float* W3   = (const float*)d_in[13];
  const float* g3   = (const float*)d_in[15];
  const float* be3  = (const float*)d_in[16];
  const float* fw1  = (const float*)d_in[17];
  const float* fb1  = (const float*)d_in[18];
  const float* fw2  = (const float*)d_in[19];
  const float* fb2  = (const float*)d_in[20];
  float* out = (float*)d_out;

  const long NH = (long)N_NODES*HDIM;          // 6.4M
  __half* Ah    = (__half*)d_ws;               // [N,H] fp16 (gemm out)
  __half* Bh    = Ah + NH;                     // [N,H] fp16 (agg out)
  __half* Wt1   = Bh + NH;                     // [128,128] fp16 transposed
  __half* Wtg   = Wt1 + 16384;
  __half* Wt3   = Wtg + 16384;
  float* dis    = (float*)(Wt3 + 16384);       // [N]
  float* al_s   = dis + N_NODES;               // [N]
  float* al_d   = al_s + N_NODES;              // [N]
  float* Pq     = al_d + N_NODES;              // [G*4,H]
  float* sc     = Pq + (long)NGRAPH*4*HDIM;    // [128] fp32
  float* sh     = sc + HDIM;                   // [128] fp32
  __half* scH   = (__half*)(sh + HDIM);        // [128] fp16
  __half* shH   = scH + HDIM;                  // [128] fp16
  int* deg_i    = (int*)(shH + HDIM);          // [N]   } zeroed
  int* fill     = deg_i + N_NODES;             // [N]   } zeroed
  float* stats  = (float*)(fill + N_NODES);    // [768] } zeroed
  int* rowp     = (int*)(stats + 768);         // [N]
  int* colx     = rowp + N_NODES;              // [E]
  int* start    = colx + N_EDGES;              // [G+1]
  int* part     = start + NGRAPH + 1;          // [256]

  hipMemsetAsync(deg_i, 0, (size_t)(2*N_NODES + 768) * sizeof(int), stream);

  const int TB = 256;
  const int gE  = (N_EDGES + TB - 1)/TB;       // 2344
  const int gMM = (N_NODES + 63)/64;           // 782
  const int gAgg= N_NODES / 4;                 // 12500 (1 wave per node)

  const _Float16* Ahf = (const _Float16*)Ah;
  const __half2*  Bh2 = (const __half2*)Bh;

  // ---- prep (weights + degree + bounds) + CSR build ----
  prep_kernel<<<192 + gE + SCAN_B, TB, 0, stream>>>(W1, Wg, W3, Wt1, Wtg, Wt3,
                                                    ei, deg_i, batch, start);
  scan_partial<<<SCAN_B, TB, 0, stream>>>(deg_i, part, dis);
  scan_offsets<<<1, TB, 0, stream>>>(part);
  scan_final<<<SCAN_B, TB, 0, stream>>>(deg_i, part, rowp);
  csr_scatter<<<gE, TB, 0, stream>>>(ei, rowp, fill, colx);

  // ---- layer 1: GCN (dis row-scale fused into gemm epilogue) ----
  gemm_mfma<false,true,false,true><<<gMM, TB, 0, stream>>>(x, Wt1, nullptr, nullptr, Ah,
                                                 nullptr, nullptr, nullptr, nullptr, dis);
  gcn_agg<<<gAgg, TB, 0, stream>>>(Ahf, dis, rowp, deg_i, colx, Bh);
  stats_h<<<512, TB, 0, stream>>>(Bh2, stats + 0, stats + 128);
  bnparam<<<1, 128, 0, stream>>>(stats + 0, stats + 128, g1, be1, sc, sh, scH, shH);

  // ---- layer 2: GAT (BN fused into gemm A-frag; att logits fused into epilogue) ----
  gemm_mfma<true,false,true,false><<<gMM, TB, 0, stream>>>(Bh, Wtg, scH, shH, Ah,
                                                 asr, adt, al_s, al_d, nullptr);
  gat_agg<<<gAgg, TB, 0, stream>>>(Ahf, al_s, al_d, rowp, deg_i, colx, Bh);
  stats_h<<<512, TB, 0, stream>>>(Bh2, stats + 256, stats + 384);
  bnparam<<<1, 128, 0, stream>>>(stats + 256, stats + 384, g2, be2, sc, sh, scH, shH);

  // ---- layer 3: GCN ----
  gemm_mfma<true,false,false,true><<<gMM, TB, 0, stream>>>(Bh, Wt3, scH, shH, Ah,
                                                 nullptr, nullptr, nullptr, nullptr, dis);
  gcn_agg<<<gAgg, TB, 0, stream>>>(Ahf, dis, rowp, deg_i, colx, Bh);
  stats_h<<<512, TB, 0, stream>>>(Bh2, stats + 512, stats + 640);
  bnparam<<<1, 128, 0, stream>>>(stats + 512, stats + 640, g3, be3, sc, sh, scH, shH);

  // ---- pool (fused BN+ReLU) + MLP head ----
  pool_h<<<NGRAPH*4, 128, 0, stream>>>(Bh, start, sc, sh, Pq);
  final_kernel<<<NGRAPH, 128, 0, stream>>>(Pq, start, fw1, fb1, fw2, fb2, out);
}

// Round 8
// 377.882 us; speedup vs baseline: 4.0442x; 1.2043x over previous
//
#include <hip/hip_runtime.h>
#include <hip/hip_fp16.h>
#include <cstdint>

#define N_NODES 50000
#define N_EDGES 600000
#define HDIM    128
#define NGRAPH  256
#define EPSBN   1e-5f
#define NEG     0.2f
#define SCAN_B  196   // ceil(50000/256)

__device__ __forceinline__ float lrelu(float v){ return v > 0.f ? v : NEG*v; }

typedef _Float16 f16x8 __attribute__((ext_vector_type(8)));
typedef float    f32x4 __attribute__((ext_vector_type(4)));

// ============ prep: weight swizzle to MFMA-fragment order + degree + bounds ===
// Wt layout: [kc][nt][q][c16][j]  (k = kc*32+q*8+j, n = nt*16+c16)
// -> B-fragment load in gemm is lane-contiguous (1KB coalesced wave load).
__global__ void prep_kernel(const float* __restrict__ W1, const float* __restrict__ Wg,
                            const float* __restrict__ W3, __half* __restrict__ Wt1,
                            __half* __restrict__ Wtg, __half* __restrict__ Wt3,
                            const int* __restrict__ ei, int* __restrict__ degi,
                            const int* __restrict__ batch, int* __restrict__ start){
  int b = blockIdx.x;
  if (b < 192){
    const float* W = (b < 64) ? W1 : (b < 128 ? Wg : W3);
    __half*     Wt = (b < 64) ? Wt1 : (b < 128 ? Wtg : Wt3);
    int idx = (b & 63)*256 + threadIdx.x;     // 0..16383
    int k = idx >> 7, n = idx & 127;
    int kc = k >> 5, q = (k >> 3) & 3, j = k & 7;
    int nt = n >> 4, c16 = n & 15;
    Wt[(((kc*8 + nt)*4 + q)*16 + c16)*8 + j] = __float2half(W[idx]);
  } else if (b < 192 + 2344){
    int e = (b - 192)*256 + threadIdx.x;
    if (e < N_EDGES) atomicAdd(&degi[ei[N_EDGES + e]], 1);
  } else {
    int i = (b - 192 - 2344)*256 + threadIdx.x;
    if (i >= N_NODES) return;
    int bb = batch[i];
    int p = (i == 0) ? -1 : batch[i-1];
    for (int g = p+1; g <= bb; ++g) start[g] = i;
    if (i == N_NODES-1)
      for (int g = bb+1; g <= NGRAPH; ++g) start[g] = N_NODES;
  }
}

// ============ MFMA GEMM: Y = act(X) @ W, fp16 out ============
// BN: per-block BN params from raw stats (S,Q,gamma,beta), applied to X frag.
// SCALE: row-scale out by dis (GCN). ATT: fused attention logits (GAT).
template<bool BN, bool F32IN, bool ATT, bool SCALE>
__global__ __launch_bounds__(256) void gemm_mfma(const void* __restrict__ Xv,
    const __half* __restrict__ Wt,
    const float* __restrict__ S, const float* __restrict__ Q,
    const float* __restrict__ gam, const float* __restrict__ bet,
    __half* __restrict__ Yh,
    const float* __restrict__ asr, const float* __restrict__ adt,
    float* __restrict__ al_s, float* __restrict__ al_d,
    const float* __restrict__ dis){
  __shared__ _Float16 scl[128], shl[128];
  const int t    = threadIdx.x;
  if (BN){
    if (t < 128){
      float mean = S[t] * (1.f/(float)N_NODES);
      float var  = fmaxf(Q[t]*(1.f/(float)N_NODES) - mean*mean, 0.f);
      float scale = gam[t]*rsqrtf(var + EPSBN);
      float shift = bet[t] - mean*scale;
      scl[t] = (_Float16)scale;
      shl[t] = (_Float16)shift;
    }
    __syncthreads();
  }
  const int wave = t >> 6, lane = t & 63;
  const int q    = lane >> 4, c16 = lane & 15;
  const int m0   = blockIdx.x*64 + wave*16;
  const int row  = m0 + c16;
  const int arow = (row > N_NODES-1) ? N_NODES-1 : row;   // tail clamp (reads only)

  f32x4 acc[8];
#pragma unroll
  for (int i = 0; i < 8; ++i) acc[i] = (f32x4){0.f,0.f,0.f,0.f};

  const f16x8* Wt8 = (const f16x8*)Wt;

#pragma unroll
  for (int kc = 0; kc < 4; ++kc){
    const int kof = kc*32 + q*8;
    f16x8 a;
    if (F32IN){
      const float* xp = (const float*)Xv + (long)arow*128 + kof;
      float4 x0 = *(const float4*)xp;
      float4 x1 = *(const float4*)(xp + 4);
      a[0]=(_Float16)x0.x; a[1]=(_Float16)x0.y; a[2]=(_Float16)x0.z; a[3]=(_Float16)x0.w;
      a[4]=(_Float16)x1.x; a[5]=(_Float16)x1.y; a[6]=(_Float16)x1.z; a[7]=(_Float16)x1.w;
    } else {
      f16x8 raw = *(const f16x8*)((const _Float16*)Xv + (long)arow*128 + kof);
      if (BN){
        f16x8 scv = *(const f16x8*)(scl + kof);
        f16x8 shv = *(const f16x8*)(shl + kof);
#pragma unroll
        for (int i = 0; i < 8; ++i){
          _Float16 v = (_Float16)(raw[i]*scv[i] + shv[i]);
          a[i] = v > (_Float16)0 ? v : (_Float16)0;
        }
      } else {
        a = raw;
      }
    }
#pragma unroll
    for (int nt = 0; nt < 8; ++nt){
      f16x8 b = Wt8[(kc*8 + nt)*64 + lane];   // lane-contiguous fragment
      acc[nt] = __builtin_amdgcn_mfma_f32_16x16x32_f16(b, a, acc[nt], 0, 0, 0);
    }
  }
  float rs = SCALE ? dis[arow] : 1.f;
  if (row < N_NODES){
    __half* yp = Yh + (long)row*128 + q*4;
#pragma unroll
    for (int nt = 0; nt < 8; ++nt){
      union { uint2 u; __half2 h[2]; } pk;
      pk.h[0] = __floats2half2_rn(acc[nt][0]*rs, acc[nt][1]*rs);
      pk.h[1] = __floats2half2_rn(acc[nt][2]*rs, acc[nt][3]*rs);
      *(uint2*)(yp + nt*16) = pk.u;
    }
  }
  if (ATT){
    float s = 0.f, d = 0.f;
#pragma unroll
    for (int nt = 0; nt < 8; ++nt){
      float4 av = *(const float4*)(asr + nt*16 + q*4);
      float4 bv = *(const float4*)(adt + nt*16 + q*4);
      s += acc[nt][0]*av.x + acc[nt][1]*av.y + acc[nt][2]*av.z + acc[nt][3]*av.w;
      d += acc[nt][0]*bv.x + acc[nt][1]*bv.y + acc[nt][2]*bv.z + acc[nt][3]*bv.w;
    }
    s += __shfl_xor(s, 16); s += __shfl_xor(s, 32);
    d += __shfl_xor(d, 16); d += __shfl_xor(d, 32);
    if (q == 0 && row < N_NODES){ al_s[row] = s; al_d[row] = d; }
  }
}

// ============ CSR build ============
__global__ void scan_partial(const int* __restrict__ degi, int* __restrict__ part,
                             float* __restrict__ dis){
  __shared__ int sm[256];
  int t = threadIdx.x; int i = blockIdx.x*256 + t;
  int v = (i < N_NODES) ? degi[i] : 0;
  if (i < N_NODES) dis[i] = rsqrtf((float)v + 1.f);   // +1 = self loop
  sm[t] = v;
  __syncthreads();
  for (int off = 128; off; off >>= 1){
    if (t < off) sm[t] += sm[t + off];
    __syncthreads();
  }
  if (t == 0) part[blockIdx.x] = sm[0];
}
// inlined block-offset (sum of part[0..b)) + block scan + writes rowp & work copy
__global__ void scan_final(const int* __restrict__ degi, const int* __restrict__ part,
                           int* __restrict__ rowp, int* __restrict__ work){
  __shared__ int sm[256];
  __shared__ int offs;
  int t = threadIdx.x; int i = blockIdx.x*256 + t;
  int pv = (t < SCAN_B && t < blockIdx.x) ? part[t] : 0;
  sm[t] = pv; __syncthreads();
  for (int off = 128; off; off >>= 1){
    if (t < off) sm[t] += sm[t + off];
    __syncthreads();
  }
  if (t == 0) offs = sm[0];
  __syncthreads();
  int v = (i < N_NODES) ? degi[i] : 0;
  sm[t] = v; __syncthreads();
  for (int off = 1; off < 256; off <<= 1){
    int add = (t >= off) ? sm[t - off] : 0;
    __syncthreads();
    sm[t] += add; __syncthreads();
  }
  if (i < N_NODES){
    int r = offs + sm[t] - v;    // exclusive prefix
    rowp[i] = r;
    work[i] = r;
  }
}
__global__ void csr_scatter(const int* __restrict__ ei, int* __restrict__ work,
                            int* __restrict__ colx){
  int e = blockIdx.x*256 + threadIdx.x;
  if (e >= N_EDGES) return;
  int s = ei[e], d = ei[N_EDGES + e];
  int pos = atomicAdd(&work[d], 1);
  colx[pos] = s;
}

// ============ GCN aggregation: weighted row-sum (w in {0,1}), 2 loads in flight
__global__ __launch_bounds__(256) void gcn_agg(const _Float16* __restrict__ Ah,
    const float* __restrict__ dis, const int* __restrict__ rowp,
    const int* __restrict__ degi, const int* __restrict__ colx,
    __half* __restrict__ Bh){
  const int n = blockIdx.x*4 + (threadIdx.x >> 6);
  const int lane = threadIdx.x & 63;
  const int g = lane >> 4, p = lane & 15;
  float acc[8] = {0,0,0,0,0,0,0,0};
  if (g == 0){
    f16x8 self = *(const f16x8*)(Ah + (long)n*128 + p*8);
#pragma unroll
    for (int i = 0; i < 8; ++i) acc[i] = (float)self[i];
  }
  const int e0 = rowp[n], cnt = degi[n];
  for (int base = 0; base < cnt; base += 64){
    int idx = base + lane;
    int s = 0; float w = 0.f;
    if (idx < cnt){ s = colx[e0 + idx]; w = 1.f; }
    int nit = min(64, cnt - base);
    int j = 0;
    for (; j + 8 <= nit; j += 8){
      int   s0 = __shfl(s, j + g),      s1 = __shfl(s, j + 4 + g);
      float w0 = __shfl(w, j + g),      w1 = __shfl(w, j + 4 + g);
      f16x8 r0 = *(const f16x8*)(Ah + (long)s0*128 + p*8);
      f16x8 r1 = *(const f16x8*)(Ah + (long)s1*128 + p*8);
#pragma unroll
      for (int i = 0; i < 8; ++i) acc[i] += w0 * (float)r0[i];
#pragma unroll
      for (int i = 0; i < 8; ++i) acc[i] += w1 * (float)r1[i];
    }
    for (; j < nit; j += 4){               // w=0 masks lanes past cnt
      int   sj = __shfl(s, j + g);
      float wj = __shfl(w, j + g);
      f16x8 r = *(const f16x8*)(Ah + (long)sj*128 + p*8);
#pragma unroll
      for (int i = 0; i < 8; ++i) acc[i] += wj * (float)r[i];
    }
  }
#pragma unroll
  for (int i = 0; i < 8; ++i){
    acc[i] += __shfl_xor(acc[i], 16);
    acc[i] += __shfl_xor(acc[i], 32);
  }
  if (g == 0){
    float dn = dis[n];
    union { uint4 u; __half2 h[4]; } pk;
#pragma unroll
    for (int i = 0; i < 4; ++i)
      pk.h[i] = __floats2half2_rn(acc[2*i]*dn, acc[2*i+1]*dn);
    *(uint4*)(Bh + (long)n*128 + p*8) = pk.u;
  }
}

// ============ GAT aggregation: single colx pass, 2 loads in flight ============
__global__ __launch_bounds__(256) void gat_agg(const _Float16* __restrict__ Ah,
    const float* __restrict__ al_s, const float* __restrict__ al_d,
    const int* __restrict__ rowp, const int* __restrict__ degi,
    const int* __restrict__ colx, __half* __restrict__ Bh){
  const int n = blockIdx.x*4 + (threadIdx.x >> 6);
  const int lane = threadIdx.x & 63;
  const int g = lane >> 4, p = lane & 15;
  const float adn = al_d[n];
  const float lself = lrelu(al_s[n] + adn);
  const int e0 = rowp[n], cnt = degi[n];
  int sReg = 0; float lv = -1e30f;
  if (lane < cnt){ sReg = colx[e0 + lane]; lv = lrelu(al_s[sReg] + adn); }
  float m = fmaxf(lself, lv);
  for (int base = 64; base < cnt; base += 64){     // rare: degree > 64
    int idx = base + lane;
    if (idx < cnt) m = fmaxf(m, lrelu(al_s[colx[e0 + idx]] + adn));
  }
#pragma unroll
  for (int off = 32; off; off >>= 1) m = fmaxf(m, __shfl_xor(m, off));
  const float exs = __expf(lself - m);
  float w = __expf(lv - m);                        // inactive lanes -> 0
  float dpart = w;
  float acc[8] = {0,0,0,0,0,0,0,0};
  if (g == 0){
    f16x8 self = *(const f16x8*)(Ah + (long)n*128 + p*8);
#pragma unroll
    for (int i = 0; i < 8; ++i) acc[i] = exs * (float)self[i];
  }
  {
    int nit = min(64, cnt);
    int j = 0;
    for (; j + 8 <= nit; j += 8){
      int   s0 = __shfl(sReg, j + g),   s1 = __shfl(sReg, j + 4 + g);
      float w0 = __shfl(w,    j + g),   w1 = __shfl(w,    j + 4 + g);
      f16x8 r0 = *(const f16x8*)(Ah + (long)s0*128 + p*8);
      f16x8 r1 = *(const f16x8*)(Ah + (long)s1*128 + p*8);
#pragma unroll
      for (int i = 0; i < 8; ++i) acc[i] += w0 * (float)r0[i];
#pragma unroll
      for (int i = 0; i < 8; ++i) acc[i] += w1 * (float)r1[i];
    }
    for (; j < nit; j += 4){                       // w=0 masks
      int   sj = __shfl(sReg, j + g);
      float wj = __shfl(w,    j + g);
      f16x8 r = *(const f16x8*)(Ah + (long)sj*128 + p*8);
#pragma unroll
      for (int i = 0; i < 8; ++i) acc[i] += wj * (float)r[i];
    }
  }
  for (int base = 64; base < cnt; base += 64){     // rare: degree > 64
    int idx = base + lane;
    int s2 = 0; float w2 = 0.f;
    if (idx < cnt){ s2 = colx[e0 + idx]; w2 = __expf(lrelu(al_s[s2] + adn) - m); }
    dpart += w2;
    int nit = min(64, cnt - base);
    for (int j = 0; j < nit; j += 4){
      int   sj = __shfl(s2, j + g);
      float wj = __shfl(w2, j + g);
      f16x8 r = *(const f16x8*)(Ah + (long)sj*128 + p*8);
#pragma unroll
      for (int i = 0; i < 8; ++i) acc[i] += wj * (float)r[i];
    }
  }
#pragma unroll
  for (int off = 32; off; off >>= 1) dpart += __shfl_xor(dpart, off);
#pragma unroll
  for (int i = 0; i < 8; ++i){
    acc[i] += __shfl_xor(acc[i], 16);
    acc[i] += __shfl_xor(acc[i], 32);
  }
  if (g == 0){
    float rinv = 1.f / (dpart + exs);
    union { uint4 u; __half2 h[4]; } pk;
#pragma unroll
    for (int i = 0; i < 4; ++i)
      pk.h[i] = __floats2half2_rn(acc[2*i]*rinv, acc[2*i+1]*rinv);
    *(uint4*)(Bh + (long)n*128 + p*8) = pk.u;
  }
}

// ============ BN stats: f16x8 loads, LDS reduce, 2 atomics/thread ============
__global__ void stats_h(const f16x8* __restrict__ X8,
                        float* __restrict__ S, float* __restrict__ Q){
  __shared__ float sb[16][16][8];
  __shared__ float qb[16][16][8];
  int t = threadIdx.x;
  int cg = t & 15, r = t >> 4;
  float s[8] = {0,0,0,0,0,0,0,0}, q[8] = {0,0,0,0,0,0,0,0};
  const int total = N_NODES*16;           // f16x8 units
  for (int idx = blockIdx.x*256 + t; idx < total; idx += gridDim.x*256){
    f16x8 v = X8[idx];
#pragma unroll
    for (int i = 0; i < 8; ++i){
      float f = (float)v[i];
      s[i] += f; q[i] += f*f;
    }
  }
#pragma unroll
  for (int i = 0; i < 8; ++i){ sb[r][cg][i] = s[i]; qb[r][cg][i] = q[i]; }
  __syncthreads();
  if (t < 128){
    int cg2 = t >> 3, j = t & 7;
    float as = 0.f, aq = 0.f;
#pragma unroll
    for (int r2 = 0; r2 < 16; ++r2){ as += sb[r2][cg2][j]; aq += qb[r2][cg2][j]; }
    atomicAdd(&S[cg2*8 + j], as);
    atomicAdd(&Q[cg2*8 + j], aq);
  }
}

// ============ fused pool (BN+ReLU+mean) + MLP head: one block per graph ========
__global__ void poolfinal(const __half* __restrict__ Bh, const int* __restrict__ start,
                          const float* __restrict__ S, const float* __restrict__ Q,
                          const float* __restrict__ gam, const float* __restrict__ bet,
                          const float* __restrict__ fw1, const float* __restrict__ fb1,
                          const float* __restrict__ fw2, const float* __restrict__ fb2,
                          float* __restrict__ out){
  __shared__ float scl[128], shl[128], psum[2][128], p[128], red[2];
  int t = threadIdx.x, gg = blockIdx.x;
  if (t < 128){
    float mean = S[t] * (1.f/(float)N_NODES);
    float var  = fmaxf(Q[t]*(1.f/(float)N_NODES) - mean*mean, 0.f);
    float scale = gam[t]*rsqrtf(var + EPSBN);
    scl[t] = scale;
    shl[t] = bet[t] - mean*scale;
  }
  __syncthreads();
  int s0 = start[gg], s1 = start[gg+1];
  int c = t & 127, h = t >> 7;
  float acc = 0.f;
  for (int n = s0 + h; n < s1; n += 2)
    acc += fmaxf(__half2float(Bh[(long)n*128 + c])*scl[c] + shl[c], 0.f);
  psum[h][c] = acc;
  __syncthreads();
  if (t < 128){
    float cnt = fmaxf((float)(s1 - s0), 1.f);
    p[t] = (psum[0][t] + psum[1][t]) / cnt;
  }
  __syncthreads();
  if (t < 128){
    float a = fb1[t];
    for (int k = 0; k < 128; ++k) a += p[k]*fw1[k*128 + t];
    float z = fmaxf(a, 0.f) * fw2[t];
    for (int off = 32; off; off >>= 1) z += __shfl_down(z, off);
    if ((t & 63) == 0) red[t >> 6] = z;
  }
  __syncthreads();
  if (t == 0) out[gg] = red[0] + red[1] + fb2[0];
}

extern "C" void kernel_launch(void* const* d_in, const int* in_sizes, int n_in,
                              void* d_out, int out_size, void* d_ws, size_t ws_size,
                              hipStream_t stream){
  const float* x    = (const float*)d_in[0];
  const int*   ei   = (const int*)d_in[1];
  const int*   batch= (const int*)d_in[2];
  const float* W1   = (const float*)d_in[3];
  const float* g1   = (const float*)d_in[5];
  const float* be1  = (const float*)d_in[6];
  const float* Wg   = (const float*)d_in[7];
  const float* asr  = (const float*)d_in[8];
  const float* adt  = (const float*)d_in[9];
  const float* g2   = (const float*)d_in[11];
  const float* be2  = (const float*)d_in[12];
  const float* W3   = (const float*)d_in[13];
  const float* g3   = (const float*)d_in[15];
  const float* be3  = (const float*)d_in[16];
  const float* fw1  = (const float*)d_in[17];
  const float* fb1  = (const float*)d_in[18];
  const float* fw2  = (const float*)d_in[19];
  const float* fb2  = (const float*)d_in[20];
  float* out = (float*)d_out;

  const long NH = (long)N_NODES*HDIM;          // 6.4M
  __half* Ah    = (__half*)d_ws;               // [N,H] fp16 (gemm out)
  __half* Bh    = Ah + NH;                     // [N,H] fp16 (agg out)
  __half* Wt1   = Bh + NH;                     // [128,128] fp16 frag-swizzled
  __half* Wtg   = Wt1 + 16384;
  __half* Wt3   = Wtg + 16384;
  float* dis    = (float*)(Wt3 + 16384);       // [N]
  float* al_s   = dis + N_NODES;               // [N]
  float* al_d   = al_s + N_NODES;              // [N]
  int* deg_i    = (int*)(al_d + N_NODES);      // [N]   } zeroed
  float* stats  = (float*)(deg_i + N_NODES);   // [768] } zeroed
  int* rowp     = (int*)(stats + 768);         // [N]
  int* work     = rowp + N_NODES;              // [N]
  int* colx     = work + N_NODES;              // [E]
  int* start    = colx + N_EDGES;              // [G+1]
  int* part     = start + NGRAPH + 1;          // [256]

  hipMemsetAsync(deg_i, 0, (size_t)(N_NODES + 768) * sizeof(int), stream);

  const int TB = 256;
  const int gE  = (N_EDGES + TB - 1)/TB;       // 2344
  const int gMM = (N_NODES + 63)/64;           // 782
  const int gAgg= N_NODES / 4;                 // 12500 (1 wave per node)

  const _Float16* Ahf = (const _Float16*)Ah;
  const f16x8*    Bh8 = (const f16x8*)Bh;

  // ---- prep (weights + degree + bounds) + CSR build ----
  prep_kernel<<<192 + gE + SCAN_B, TB, 0, stream>>>(W1, Wg, W3, Wt1, Wtg, Wt3,
                                                    ei, deg_i, batch, start);
  scan_partial<<<SCAN_B, TB, 0, stream>>>(deg_i, part, dis);
  scan_final<<<SCAN_B, TB, 0, stream>>>(deg_i, part, rowp, work);
  csr_scatter<<<gE, TB, 0, stream>>>(ei, work, colx);

  // ---- layer 1: GCN (dis row-scale fused into gemm epilogue) ----
  gemm_mfma<false,true,false,true><<<gMM, TB, 0, stream>>>(x, Wt1,
      nullptr, nullptr, nullptr, nullptr, Ah, nullptr, nullptr, nullptr, nullptr, dis);
  gcn_agg<<<gAgg, TB, 0, stream>>>(Ahf, dis, rowp, deg_i, colx, Bh);
  stats_h<<<512, TB, 0, stream>>>(Bh8, stats + 0, stats + 128);

  // ---- layer 2: GAT (BN params computed in-block; att logits fused) ----
  gemm_mfma<true,false,true,false><<<gMM, TB, 0, stream>>>(Bh, Wtg,
      stats + 0, stats + 128, g1, be1, Ah, asr, adt, al_s, al_d, nullptr);
  gat_agg<<<gAgg, TB, 0, stream>>>(Ahf, al_s, al_d, rowp, deg_i, colx, Bh);
  stats_h<<<512, TB, 0, stream>>>(Bh8, stats + 256, stats + 384);

  // ---- layer 3: GCN ----
  gemm_mfma<true,false,false,true><<<gMM, TB, 0, stream>>>(Bh, Wt3,
      stats + 256, stats + 384, g2, be2, Ah, nullptr, nullptr, nullptr, nullptr, dis);
  gcn_agg<<<gAgg, TB, 0, stream>>>(Ahf, dis, rowp, deg_i, colx, Bh);
  stats_h<<<512, TB, 0, stream>>>(Bh8, stats + 512, stats + 640);

  // ---- fused pool + MLP head ----
  poolfinal<<<NGRAPH, TB, 0, stream>>>(Bh, start, stats + 512, stats + 640, g3, be3,
                                       fw1, fb1, fw2, fb2, out);
}